// Round 1
// baseline (206.116 us; speedup 1.0000x reference)
//
#include <hip/hip_runtime.h>
#include <math.h>

// ---------------------------------------------------------------------------
// BiMultiHeadAttention fused pipeline (MI355X / gfx950)
//   B=4 N=2048 E=256 H=8 D=32   (bh = B*H = 32 heads total)
//
// Stages (all bf16 MFMA, fp32 softmax/LN):
//   1) prep_x    : f32 -> bf16 for x_l, x_r, (x_l - x_r)
//   2) prep_w    : W[k][n] f32 -> bf16 W^T[n][k] for Wq,Wk,Wv,Wp
//   3) qkv_gemm  : Q = (x_l Wq + bq) * (1/sqrt(D)*log2e)  [bh][n][32] bf16
//                  K = (x_r Wk + bk)                       [bh][n][32] bf16
//                  V^T = ((x_l-x_r) Wv + bv)^T             [bh][32][n] bf16
//   4) attn_pass1: flash attention (online softmax, exp2 domain) -> out_l,
//                  stats M[q] = m_q + log2(l_q)   (one float per row!)
//   5) attn_pass2: out_r[k] = sum_q 2^(s(q,k)-M_q) v[q]   == attn^T @ v
//   6) proj_ln   : y = AO @ Wp + bp ; LayerNorm(g,b) ; + residual -> f32
// ---------------------------------------------------------------------------

typedef __attribute__((ext_vector_type(8))) short short8;   // 8 bf16 (4 VGPR)
typedef __attribute__((ext_vector_type(4))) float f32x4;
typedef __attribute__((ext_vector_type(4))) unsigned short u16x4;

__device__ __forceinline__ unsigned short bf16_rn(float f) {
    union { float f; unsigned int u; } c; c.f = f;
    return (unsigned short)((c.u + 0x7FFFu + ((c.u >> 16) & 1u)) >> 16);
}

#if __has_builtin(__builtin_amdgcn_exp2f)
__device__ __forceinline__ float fexp2(float x) { return __builtin_amdgcn_exp2f(x); }
#else
__device__ __forceinline__ float fexp2(float x) { return exp2f(x); }
#endif
#if __has_builtin(__builtin_amdgcn_logf)
__device__ __forceinline__ float flog2(float x) { return __builtin_amdgcn_logf(x); }
#else
__device__ __forceinline__ float flog2(float x) { return log2f(x); }
#endif

__device__ __forceinline__ f32x4 mfma16(short8 a, short8 b, f32x4 c) {
    return __builtin_amdgcn_mfma_f32_16x16x32_bf16(a, b, c, 0, 0, 0);
}

// ---------------------------------------------------------------------------
// 1) f32 -> bf16 conversion of the two streams + their difference
// ---------------------------------------------------------------------------
__global__ void prep_x(const float* __restrict__ xl, const float* __restrict__ xr,
                       unsigned short* __restrict__ xlb, unsigned short* __restrict__ xrb,
                       unsigned short* __restrict__ xdb) {
    const size_t i = ((size_t)blockIdx.x * 256 + threadIdx.x) * 4;
    const float4 A = *(const float4*)(xl + i);
    const float4 Bv = *(const float4*)(xr + i);
    u16x4 pa = { bf16_rn(A.x), bf16_rn(A.y), bf16_rn(A.z), bf16_rn(A.w) };
    u16x4 pb = { bf16_rn(Bv.x), bf16_rn(Bv.y), bf16_rn(Bv.z), bf16_rn(Bv.w) };
    u16x4 pd = { bf16_rn(A.x - Bv.x), bf16_rn(A.y - Bv.y),
                 bf16_rn(A.z - Bv.z), bf16_rn(A.w - Bv.w) };
    *(u16x4*)(xlb + i) = pa;
    *(u16x4*)(xrb + i) = pb;
    *(u16x4*)(xdb + i) = pd;
}

// ---------------------------------------------------------------------------
// 2) transpose + convert the four 256x256 weight matrices: Wt[n][k] = W[k][n]
// ---------------------------------------------------------------------------
__global__ void prep_w(const float* __restrict__ Wq, const float* __restrict__ Wk,
                       const float* __restrict__ Wv, const float* __restrict__ Wp,
                       unsigned short* __restrict__ Wqt, unsigned short* __restrict__ Wkt,
                       unsigned short* __restrict__ Wvt, unsigned short* __restrict__ Wpt) {
    const int gid = blockIdx.x * 256 + threadIdx.x;       // 0 .. 262143
    const int m = gid >> 16;
    const int idx = gid & 65535;
    const int k = idx >> 8, n = idx & 255;
    const float* W = (m == 0) ? Wq : (m == 1) ? Wk : (m == 2) ? Wv : Wp;
    unsigned short* Wt = (m == 0) ? Wqt : (m == 1) ? Wkt : (m == 2) ? Wvt : Wpt;
    Wt[n * 256 + k] = bf16_rn(W[(size_t)k * 256 + n]);    // read coalesced, L2 absorbs write
}

// ---------------------------------------------------------------------------
// 3) QKV projection GEMM: [8192,256] x [256,256] + bias, 3 outputs (z-dim)
//    block = 256 thr (4 waves 2x2), tile 128x64, K-step 32
// ---------------------------------------------------------------------------
__launch_bounds__(256)
__global__ void qkv_gemm(const unsigned short* __restrict__ xlb,
                         const unsigned short* __restrict__ xrb,
                         const unsigned short* __restrict__ xdb,
                         const unsigned short* __restrict__ Wqt,
                         const unsigned short* __restrict__ Wkt,
                         const unsigned short* __restrict__ Wvt,
                         const float* __restrict__ bq, const float* __restrict__ bk,
                         const float* __restrict__ bv,
                         unsigned short* __restrict__ Qg, unsigned short* __restrict__ Kg,
                         unsigned short* __restrict__ Vtg) {
    const int z = blockIdx.z;
    const unsigned short* A  = (z == 0) ? xlb : (z == 1) ? xrb : xdb;
    const unsigned short* Wt = (z == 0) ? Wqt : (z == 1) ? Wkt : Wvt;
    const float* bias        = (z == 0) ? bq  : (z == 1) ? bk  : bv;

    __shared__ unsigned short At[128][40];   // 32 cols + 8 pad (80B = 16B-mult)
    __shared__ unsigned short Bt[64][40];

    const int tid = threadIdx.x;
    const int lane = tid & 63, wv = tid >> 6;
    const int a = lane & 15, g = lane >> 4;
    const int wr = wv >> 1, wc = wv & 1;
    const int r0 = blockIdx.x * 128;
    const int c0 = blockIdx.y * 64;

    const f32x4 fz = {0.f, 0.f, 0.f, 0.f};
    f32x4 acc[4][2];
#pragma unroll
    for (int f = 0; f < 4; ++f)
#pragma unroll
        for (int t = 0; t < 2; ++t) acc[f][t] = fz;

    const int arow = tid >> 1, aoff = (tid & 1) * 16;
    const int brow = tid >> 2, boff = (tid & 3) * 8;

    for (int ks = 0; ks < 8; ++ks) {
        __syncthreads();
        {
            const unsigned short* asrc = A + (size_t)(r0 + arow) * 256 + ks * 32 + aoff;
            *(short8*)&At[arow][aoff]     = *(const short8*)asrc;
            *(short8*)&At[arow][aoff + 8] = *(const short8*)(asrc + 8);
            *(short8*)&Bt[brow][boff] =
                *(const short8*)(Wt + (size_t)(c0 + brow) * 256 + ks * 32 + boff);
        }
        __syncthreads();
        short8 af[4], bfr[2];
#pragma unroll
        for (int f = 0; f < 4; ++f) af[f] = *(const short8*)&At[wr * 64 + f * 16 + a][g * 8];
#pragma unroll
        for (int t = 0; t < 2; ++t) bfr[t] = *(const short8*)&Bt[wc * 32 + t * 16 + a][g * 8];
#pragma unroll
        for (int f = 0; f < 4; ++f)
#pragma unroll
            for (int t = 0; t < 2; ++t) acc[f][t] = mfma16(af[f], bfr[t], acc[f][t]);
    }

    // epilogue: +bias (and fold softmax scale*log2e into Q)
    const float scq = 0.17677669529663687f * 1.4426950408889634f;
#pragma unroll
    for (int t = 0; t < 2; ++t) {
        const int C = c0 + wc * 32 + t * 16 + a;
        const float bb = bias[C];
        const int h = C >> 5, d = C & 31;
#pragma unroll
        for (int f = 0; f < 4; ++f) {
            const int Rb = r0 + wr * 64 + f * 16 + g * 4;      // rows Rb..Rb+3
            const int b_ = Rb >> 11, n = Rb & 2047;
            const int bhh = b_ * 8 + h;
            float v[4];
#pragma unroll
            for (int r = 0; r < 4; ++r) {
                v[r] = acc[f][t][r] + bb;
                if (z == 0) v[r] *= scq;
            }
            if (z < 2) {
                unsigned short* dst = ((z == 0) ? Qg : Kg) + (size_t)(bhh * 2048 + n) * 32 + d;
#pragma unroll
                for (int r = 0; r < 4; ++r) dst[(size_t)r * 32] = bf16_rn(v[r]);
            } else {  // V transposed: [bh][d][n]; 4 consecutive n -> one 8B store
                u16x4 pk = { bf16_rn(v[0]), bf16_rn(v[1]), bf16_rn(v[2]), bf16_rn(v[3]) };
                *(u16x4*)(Vtg + (size_t)(bhh * 32 + d) * 2048 + n) = pk;
            }
        }
    }
}

// ---------------------------------------------------------------------------
// 4) pass 1: flash attention -> out_l (bf16) + M = m + log2(l)  (exp2 domain)
//    block = 4 waves, each wave owns 16 q-rows; k-tiles of 64
// ---------------------------------------------------------------------------
__launch_bounds__(256)
__global__ void attn_pass1(const unsigned short* __restrict__ Qg,
                           const unsigned short* __restrict__ Kg,
                           const unsigned short* __restrict__ Vtg,
                           unsigned short* __restrict__ AOl,
                           float* __restrict__ Mg) {
    __shared__ unsigned short Kt[64][40];
    __shared__ unsigned short Vt[32][72];
    __shared__ unsigned short Pl[4][16][72];

    const int bh = blockIdx.y;
    const int tid = threadIdx.x;
    const int lane = tid & 63, wv = tid >> 6;
    const int a = lane & 15, g = lane >> 4;
    const int q0 = blockIdx.x * 64 + wv * 16;

    // Q fragment (A operand, rows=q, K-dim=D=32) hoisted for the whole kernel
    const short8 qf = *(const short8*)(Qg + (size_t)(bh * 2048 + q0 + a) * 32 + g * 8);

    const f32x4 fz = {0.f, 0.f, 0.f, 0.f};
    f32x4 accL0 = fz, accL1 = fz;
    float m_run[4], l_run[4];
#pragma unroll
    for (int r = 0; r < 4; ++r) { m_run[r] = -3.0e38f; l_run[r] = 0.f; }

    const int krow = tid >> 2, koff = (tid & 3) * 8;
    const int vrow = tid >> 3, voff = (tid & 7) * 8;
    const unsigned short* Ksrc = Kg + (size_t)(bh * 2048 + krow) * 32 + koff;
    const unsigned short* Vsrc = Vtg + (size_t)(bh * 32 + vrow) * 2048 + voff;

    for (int kt = 0; kt < 32; ++kt) {
        const int k0 = kt * 64;
        __syncthreads();
        *(short8*)&Kt[krow][koff] = *(const short8*)(Ksrc + (size_t)k0 * 32);
        *(short8*)&Vt[vrow][voff] = *(const short8*)(Vsrc + k0);
        __syncthreads();

        // S tile 16 x 64 : 4 MFMAs (D=32 in one shot); S[g*4+r][t*16+a]
        f32x4 s[4];
#pragma unroll
        for (int t = 0; t < 4; ++t)
            s[t] = mfma16(qf, *(const short8*)&Kt[t * 16 + a][g * 8], fz);

        float mt[4], al[4], p[4][4], rs[4];
#pragma unroll
        for (int r = 0; r < 4; ++r)
            mt[r] = fmaxf(fmaxf(s[0][r], s[1][r]), fmaxf(s[2][r], s[3][r]));
#pragma unroll
        for (int mask = 1; mask <= 8; mask <<= 1)
#pragma unroll
            for (int r = 0; r < 4; ++r) mt[r] = fmaxf(mt[r], __shfl_xor(mt[r], mask));
#pragma unroll
        for (int r = 0; r < 4; ++r) {
            const float mn = fmaxf(m_run[r], mt[r]);
            al[r] = fexp2(m_run[r] - mn);
            m_run[r] = mn;
        }
#pragma unroll
        for (int t = 0; t < 4; ++t)
#pragma unroll
            for (int r = 0; r < 4; ++r) p[t][r] = fexp2(s[t][r] - m_run[r]);
#pragma unroll
        for (int r = 0; r < 4; ++r) rs[r] = (p[0][r] + p[1][r]) + (p[2][r] + p[3][r]);
#pragma unroll
        for (int mask = 1; mask <= 8; mask <<= 1)
#pragma unroll
            for (int r = 0; r < 4; ++r) rs[r] += __shfl_xor(rs[r], mask);
#pragma unroll
        for (int r = 0; r < 4; ++r) {
            l_run[r] = l_run[r] * al[r] + rs[r];
            accL0[r] *= al[r];
            accL1[r] *= al[r];
        }
        // P -> LDS (per-wave private) so it can be re-read as MFMA A-fragments
#pragma unroll
        for (int t = 0; t < 4; ++t)
#pragma unroll
            for (int r = 0; r < 4; ++r)
                Pl[wv][g * 4 + r][t * 16 + a] = bf16_rn(p[t][r]);
        // PV: accL[d-frag] += P[16x64] @ V[64x32]
#pragma unroll
        for (int kk = 0; kk < 2; ++kk) {
            const short8 pa = *(const short8*)&Pl[wv][a][kk * 32 + g * 8];
            accL0 = mfma16(pa, *(const short8*)&Vt[a][kk * 32 + g * 8], accL0);
            accL1 = mfma16(pa, *(const short8*)&Vt[16 + a][kk * 32 + g * 8], accL1);
        }
    }

    // epilogue: normalize, store out_l bf16 [8192][256]; store M stats
    const int b_ = bh >> 3, h = bh & 7;
    float rl[4];
#pragma unroll
    for (int r = 0; r < 4; ++r) rl[r] = 1.0f / l_run[r];
#pragma unroll
    for (int r = 0; r < 4; ++r) {
        const int n = q0 + g * 4 + r;
        unsigned short* dst = AOl + (size_t)(b_ * 2048 + n) * 256 + h * 32 + a;
        dst[0]  = bf16_rn(accL0[r] * rl[r]);
        dst[16] = bf16_rn(accL1[r] * rl[r]);
    }
    if (a < 4) {
        const int r = a;
        const int n = q0 + g * 4 + r;
        const float mv = (r == 0) ? m_run[0] : (r == 1) ? m_run[1] : (r == 2) ? m_run[2] : m_run[3];
        const float lv = (r == 0) ? l_run[0] : (r == 1) ? l_run[1] : (r == 2) ? l_run[2] : l_run[3];
        Mg[bh * 2048 + n] = mv + flog2(lv);
    }
}

// ---------------------------------------------------------------------------
// 5) pass 2: out_r = attn^T @ v.  Block owns 64 k-rows, iterates q-tiles.
//    p = 2^(s - M_q) is already fully normalized -> plain accumulation.
// ---------------------------------------------------------------------------
__launch_bounds__(256)
__global__ void attn_pass2(const unsigned short* __restrict__ Qg,
                           const unsigned short* __restrict__ Kg,
                           const unsigned short* __restrict__ Vtg,
                           const float* __restrict__ Mg,
                           unsigned short* __restrict__ AOr) {
    __shared__ unsigned short Qt[64][40];
    __shared__ unsigned short Vt[32][72];
    __shared__ unsigned short Pl[4][16][72];

    const int bh = blockIdx.y;
    const int tid = threadIdx.x;
    const int lane = tid & 63, wv = tid >> 6;
    const int a = lane & 15, g = lane >> 4;
    const int k0 = blockIdx.x * 64 + wv * 16;

    const short8 kf = *(const short8*)(Kg + (size_t)(bh * 2048 + k0 + a) * 32 + g * 8);

    const f32x4 fz = {0.f, 0.f, 0.f, 0.f};
    f32x4 acc0 = fz, acc1 = fz;

    const int qrow = tid >> 2, qoff = (tid & 3) * 8;
    const int vrow = tid >> 3, voff = (tid & 7) * 8;
    const unsigned short* Qsrc = Qg + (size_t)(bh * 2048 + qrow) * 32 + qoff;
    const unsigned short* Vsrc = Vtg + (size_t)(bh * 32 + vrow) * 2048 + voff;

    for (int qt = 0; qt < 32; ++qt) {
        const int qq = qt * 64;
        __syncthreads();
        *(short8*)&Qt[qrow][qoff] = *(const short8*)(Qsrc + (size_t)qq * 32);
        *(short8*)&Vt[vrow][voff] = *(const short8*)(Vsrc + qq);
        __syncthreads();

        float Mq[4];
#pragma unroll
        for (int t = 0; t < 4; ++t) Mq[t] = Mg[bh * 2048 + qq + t * 16 + a];

        // S^T tile: rows=k-local, cols=q ; then P^T = 2^(s - M_q)
#pragma unroll
        for (int t = 0; t < 4; ++t) {
            const f32x4 s = mfma16(kf, *(const short8*)&Qt[t * 16 + a][g * 8], fz);
#pragma unroll
            for (int r = 0; r < 4; ++r)
                Pl[wv][g * 4 + r][t * 16 + a] = bf16_rn(fexp2(s[r] - Mq[t]));
        }
#pragma unroll
        for (int kk = 0; kk < 2; ++kk) {
            const short8 pa = *(const short8*)&Pl[wv][a][kk * 32 + g * 8];
            acc0 = mfma16(pa, *(const short8*)&Vt[a][kk * 32 + g * 8], acc0);
            acc1 = mfma16(pa, *(const short8*)&Vt[16 + a][kk * 32 + g * 8], acc1);
        }
    }

    const int b_ = bh >> 3, h = bh & 7;
#pragma unroll
    for (int r = 0; r < 4; ++r) {
        const int n = k0 + g * 4 + r;
        unsigned short* dst = AOr + (size_t)(b_ * 2048 + n) * 256 + h * 32 + a;
        dst[0]  = bf16_rn(acc0[r]);
        dst[16] = bf16_rn(acc1[r]);
    }
}

// ---------------------------------------------------------------------------
// 6) output projection + LayerNorm + residual (fp32 out)
//    block = 4 waves, 64 rows x 256 cols, K=256 in 8 steps; LN per row
// ---------------------------------------------------------------------------
__launch_bounds__(256)
__global__ void proj_ln(const unsigned short* __restrict__ AO,
                        const unsigned short* __restrict__ Wpt,
                        const float* __restrict__ bp,
                        const float* __restrict__ gamma, const float* __restrict__ beta,
                        const float* __restrict__ xres,
                        float* __restrict__ out) {
    __shared__ unsigned short At[64][264];   // 256 + 8 pad (528B stride)
    __shared__ unsigned short Bt[256][40];

    const int tid = threadIdx.x;
    const int lane = tid & 63, wv = tid >> 6;
    const int a = lane & 15, g = lane >> 4;
    const int r0 = blockIdx.x * 64;

    {   // stage the whole 64x256 A block once
        const int row = tid >> 2, seg = (tid & 3) * 64;
        const unsigned short* src = AO + (size_t)(r0 + row) * 256 + seg;
#pragma unroll
        for (int i = 0; i < 8; ++i)
            *(short8*)&At[row][seg + i * 8] = *(const short8*)(src + i * 8);
    }

    const f32x4 fz = {0.f, 0.f, 0.f, 0.f};
    f32x4 acc[16];
#pragma unroll
    for (int cf = 0; cf < 16; ++cf) acc[cf] = fz;

    for (int ks = 0; ks < 8; ++ks) {
        __syncthreads();
        {   // stage W^T slab [256 cols][32 k]
            const unsigned short* src = Wpt + (size_t)tid * 256 + ks * 32;
#pragma unroll
            for (int i = 0; i < 4; ++i)
                *(short8*)&Bt[tid][i * 8] = *(const short8*)(src + i * 8);
        }
        __syncthreads();
        const short8 af = *(const short8*)&At[wv * 16 + a][ks * 32 + g * 8];
#pragma unroll
        for (int cf = 0; cf < 16; ++cf) {
            const short8 bfr = *(const short8*)&Bt[cf * 16 + a][g * 8];
            acc[cf] = mfma16(af, bfr, acc[cf]);
        }
    }

    // epilogue: bias + LayerNorm + residual
    float bb[16], gg[16], be[16];
#pragma unroll
    for (int cf = 0; cf < 16; ++cf) {
        const int c = cf * 16 + a;
        bb[cf] = bp[c]; gg[cf] = gamma[c]; be[cf] = beta[c];
    }
#pragma unroll
    for (int r = 0; r < 4; ++r) {
        float y[16];
        float s1 = 0.f, s2 = 0.f;
#pragma unroll
        for (int cf = 0; cf < 16; ++cf) {
            y[cf] = acc[cf][r] + bb[cf];
            s1 += y[cf];
            s2 += y[cf] * y[cf];
        }
#pragma unroll
        for (int mask = 1; mask <= 8; mask <<= 1) {
            s1 += __shfl_xor(s1, mask);
            s2 += __shfl_xor(s2, mask);
        }
        const float mu = s1 * (1.0f / 256.0f);
        const float var = s2 * (1.0f / 256.0f) - mu * mu;
        const float rstd = rsqrtf(var + 1e-5f);
        const int R = r0 + wv * 16 + g * 4 + r;
#pragma unroll
        for (int cf = 0; cf < 16; ++cf) {
            const int c = cf * 16 + a;
            out[(size_t)R * 256 + c] =
                (y[cf] - mu) * rstd * gg[cf] + be[cf] + xres[(size_t)R * 256 + c];
        }
    }
}

// ---------------------------------------------------------------------------
extern "C" void kernel_launch(void* const* d_in, const int* in_sizes, int n_in,
                              void* d_out, int out_size, void* d_ws, size_t ws_size,
                              hipStream_t stream) {
    const float* x_l  = (const float*)d_in[0];
    const float* x_r  = (const float*)d_in[1];
    const float* Wq   = (const float*)d_in[2];
    const float* bq   = (const float*)d_in[3];
    const float* Wk   = (const float*)d_in[4];
    const float* bk   = (const float*)d_in[5];
    const float* Wv   = (const float*)d_in[6];
    const float* bv   = (const float*)d_in[7];
    const float* Wp   = (const float*)d_in[8];
    const float* bp   = (const float*)d_in[9];
    const float* ln_g = (const float*)d_in[10];
    const float* ln_b = (const float*)d_in[11];
    const float* rn_g = (const float*)d_in[12];
    const float* rn_b = (const float*)d_in[13];

    const size_t SZ_TOK = (size_t)8192 * 256;   // 2,097,152 elems per [B,N,E]

    unsigned short* xl_bf = (unsigned short*)d_ws;      // reused as AOl later
    unsigned short* xr_bf = xl_bf + SZ_TOK;             // reused as AOr later
    unsigned short* xd_bf = xr_bf + SZ_TOK;
    unsigned short* Qg    = xd_bf + SZ_TOK;
    unsigned short* Kg    = Qg + SZ_TOK;
    unsigned short* Vtg   = Kg + SZ_TOK;
    unsigned short* Wqt   = Vtg + SZ_TOK;
    unsigned short* Wkt   = Wqt + 65536;
    unsigned short* Wvt   = Wkt + 65536;
    unsigned short* Wpt   = Wvt + 65536;
    float*          Mg    = (float*)(Wpt + 65536);
    unsigned short* AOl   = xl_bf;   // safe: qkv_gemm (last reader) runs before pass1
    unsigned short* AOr   = xr_bf;
    float* out = (float*)d_out;

    prep_x<<<2048, 256, 0, stream>>>(x_l, x_r, xl_bf, xr_bf, xd_bf);
    prep_w<<<1024, 256, 0, stream>>>(Wq, Wk, Wv, Wp, Wqt, Wkt, Wvt, Wpt);
    qkv_gemm<<<dim3(64, 4, 3), 256, 0, stream>>>(xl_bf, xr_bf, xd_bf,
                                                 Wqt, Wkt, Wvt, bq, bk, bv, Qg, Kg, Vtg);
    attn_pass1<<<dim3(32, 32), 256, 0, stream>>>(Qg, Kg, Vtg, AOl, Mg);
    attn_pass2<<<dim3(32, 32), 256, 0, stream>>>(Qg, Kg, Vtg, Mg, AOr);
    proj_ln<<<128, 256, 0, stream>>>(AOl, Wpt, bp, ln_g, ln_b, x_l, out);
    proj_ln<<<128, 256, 0, stream>>>(AOr, Wpt, bp, rn_g, rn_b, x_r, out + SZ_TOK);
}

// Round 2
// 190.650 us; speedup vs baseline: 1.0811x; 1.0811x over previous
//
#include <hip/hip_runtime.h>
#include <math.h>

// ---------------------------------------------------------------------------
// BiMultiHeadAttention fused pipeline (MI355X / gfx950)
//   B=4 N=2048 E=256 H=8 D=32   (bh = B*H = 32 heads total)
//
// Round 2: attention passes rewritten m214-style:
//   - 32x32x16 bf16 MFMA, swapped operands (S^T = K @ Q^T orientation)
//   - fixed softmax max (M=8, exp2-domain): no max-reduce, no rescale
//   - P kept in registers: v_cvt_pk_bf16_f32 + shfl_xor(32) redistribution
//   - K/V read directly from global (L2-resident), 1-deep prefetch
//   - ZERO LDS, ZERO barriers in both attention passes
// ---------------------------------------------------------------------------

typedef __attribute__((ext_vector_type(8))) short short8;   // 8 bf16 (4 VGPR)
typedef __attribute__((ext_vector_type(4))) float f32x4;
typedef __attribute__((ext_vector_type(16))) float f32x16;
typedef __attribute__((ext_vector_type(4))) unsigned short u16x4;

union FragU { unsigned int u[4]; short8 s8; };

__device__ __forceinline__ unsigned short bf16_rn(float f) {
    union { float f; unsigned int u; } c; c.f = f;
    return (unsigned short)((c.u + 0x7FFFu + ((c.u >> 16) & 1u)) >> 16);
}

#if __has_builtin(__builtin_amdgcn_exp2f)
__device__ __forceinline__ float fexp2(float x) { return __builtin_amdgcn_exp2f(x); }
#else
__device__ __forceinline__ float fexp2(float x) { return exp2f(x); }
#endif
#if __has_builtin(__builtin_amdgcn_logf)
__device__ __forceinline__ float flog2(float x) { return __builtin_amdgcn_logf(x); }
#else
__device__ __forceinline__ float flog2(float x) { return log2f(x); }
#endif

__device__ __forceinline__ f32x4 mfma16(short8 a, short8 b, f32x4 c) {
    return __builtin_amdgcn_mfma_f32_16x16x32_bf16(a, b, c, 0, 0, 0);
}
__device__ __forceinline__ f32x16 mfma32(short8 a, short8 b, f32x16 c) {
    return __builtin_amdgcn_mfma_f32_32x32x16_bf16(a, b, c, 0, 0, 0);
}

// ---------------------------------------------------------------------------
// 1) f32 -> bf16 conversion of the two streams + their difference
// ---------------------------------------------------------------------------
__global__ void prep_x(const float* __restrict__ xl, const float* __restrict__ xr,
                       unsigned short* __restrict__ xlb, unsigned short* __restrict__ xrb,
                       unsigned short* __restrict__ xdb) {
    const size_t i = ((size_t)blockIdx.x * 256 + threadIdx.x) * 4;
    const float4 A = *(const float4*)(xl + i);
    const float4 Bv = *(const float4*)(xr + i);
    u16x4 pa = { bf16_rn(A.x), bf16_rn(A.y), bf16_rn(A.z), bf16_rn(A.w) };
    u16x4 pb = { bf16_rn(Bv.x), bf16_rn(Bv.y), bf16_rn(Bv.z), bf16_rn(Bv.w) };
    u16x4 pd = { bf16_rn(A.x - Bv.x), bf16_rn(A.y - Bv.y),
                 bf16_rn(A.z - Bv.z), bf16_rn(A.w - Bv.w) };
    *(u16x4*)(xlb + i) = pa;
    *(u16x4*)(xrb + i) = pb;
    *(u16x4*)(xdb + i) = pd;
}

// ---------------------------------------------------------------------------
// 2) transpose + convert the four 256x256 weight matrices: Wt[n][k] = W[k][n]
// ---------------------------------------------------------------------------
__global__ void prep_w(const float* __restrict__ Wq, const float* __restrict__ Wk,
                       const float* __restrict__ Wv, const float* __restrict__ Wp,
                       unsigned short* __restrict__ Wqt, unsigned short* __restrict__ Wkt,
                       unsigned short* __restrict__ Wvt, unsigned short* __restrict__ Wpt) {
    const int gid = blockIdx.x * 256 + threadIdx.x;       // 0 .. 262143
    const int m = gid >> 16;
    const int idx = gid & 65535;
    const int k = idx >> 8, n = idx & 255;
    const float* W = (m == 0) ? Wq : (m == 1) ? Wk : (m == 2) ? Wv : Wp;
    unsigned short* Wt = (m == 0) ? Wqt : (m == 1) ? Wkt : (m == 2) ? Wvt : Wpt;
    Wt[n * 256 + k] = bf16_rn(W[(size_t)k * 256 + n]);
}

// ---------------------------------------------------------------------------
// 3) QKV projection GEMM: [8192,256] x [256,256] + bias, 3 outputs (z-dim)
// ---------------------------------------------------------------------------
__launch_bounds__(256)
__global__ void qkv_gemm(const unsigned short* __restrict__ xlb,
                         const unsigned short* __restrict__ xrb,
                         const unsigned short* __restrict__ xdb,
                         const unsigned short* __restrict__ Wqt,
                         const unsigned short* __restrict__ Wkt,
                         const unsigned short* __restrict__ Wvt,
                         const float* __restrict__ bq, const float* __restrict__ bk,
                         const float* __restrict__ bv,
                         unsigned short* __restrict__ Qg, unsigned short* __restrict__ Kg,
                         unsigned short* __restrict__ Vtg) {
    const int z = blockIdx.z;
    const unsigned short* A  = (z == 0) ? xlb : (z == 1) ? xrb : xdb;
    const unsigned short* Wt = (z == 0) ? Wqt : (z == 1) ? Wkt : Wvt;
    const float* bias        = (z == 0) ? bq  : (z == 1) ? bk  : bv;

    __shared__ unsigned short At[128][40];
    __shared__ unsigned short Bt[64][40];

    const int tid = threadIdx.x;
    const int lane = tid & 63, wv = tid >> 6;
    const int a = lane & 15, g = lane >> 4;
    const int wr = wv >> 1, wc = wv & 1;
    const int r0 = blockIdx.x * 128;
    const int c0 = blockIdx.y * 64;

    const f32x4 fz = {0.f, 0.f, 0.f, 0.f};
    f32x4 acc[4][2];
#pragma unroll
    for (int f = 0; f < 4; ++f)
#pragma unroll
        for (int t = 0; t < 2; ++t) acc[f][t] = fz;

    const int arow = tid >> 1, aoff = (tid & 1) * 16;
    const int brow = tid >> 2, boff = (tid & 3) * 8;

    for (int ks = 0; ks < 8; ++ks) {
        __syncthreads();
        {
            const unsigned short* asrc = A + (size_t)(r0 + arow) * 256 + ks * 32 + aoff;
            *(short8*)&At[arow][aoff]     = *(const short8*)asrc;
            *(short8*)&At[arow][aoff + 8] = *(const short8*)(asrc + 8);
            *(short8*)&Bt[brow][boff] =
                *(const short8*)(Wt + (size_t)(c0 + brow) * 256 + ks * 32 + boff);
        }
        __syncthreads();
        short8 af[4], bfr[2];
#pragma unroll
        for (int f = 0; f < 4; ++f) af[f] = *(const short8*)&At[wr * 64 + f * 16 + a][g * 8];
#pragma unroll
        for (int t = 0; t < 2; ++t) bfr[t] = *(const short8*)&Bt[wc * 32 + t * 16 + a][g * 8];
#pragma unroll
        for (int f = 0; f < 4; ++f)
#pragma unroll
            for (int t = 0; t < 2; ++t) acc[f][t] = mfma16(af[f], bfr[t], acc[f][t]);
    }

    const float scq = 0.17677669529663687f * 1.4426950408889634f;
#pragma unroll
    for (int t = 0; t < 2; ++t) {
        const int C = c0 + wc * 32 + t * 16 + a;
        const float bb = bias[C];
        const int h = C >> 5, d = C & 31;
#pragma unroll
        for (int f = 0; f < 4; ++f) {
            const int Rb = r0 + wr * 64 + f * 16 + g * 4;
            const int b_ = Rb >> 11, n = Rb & 2047;
            const int bhh = b_ * 8 + h;
            float v[4];
#pragma unroll
            for (int r = 0; r < 4; ++r) {
                v[r] = acc[f][t][r] + bb;
                if (z == 0) v[r] *= scq;
            }
            if (z < 2) {
                unsigned short* dst = ((z == 0) ? Qg : Kg) + (size_t)(bhh * 2048 + n) * 32 + d;
#pragma unroll
                for (int r = 0; r < 4; ++r) dst[(size_t)r * 32] = bf16_rn(v[r]);
            } else {
                u16x4 pk = { bf16_rn(v[0]), bf16_rn(v[1]), bf16_rn(v[2]), bf16_rn(v[3]) };
                *(u16x4*)(Vtg + (size_t)(bhh * 32 + d) * 2048 + n) = pk;
            }
        }
    }
}

// ---------------------------------------------------------------------------
// Redistribution helper: S^T regs (k-local = (j&3)+8*(j>>2)+4*hi) -> MFMA
// operand fragment needing contract-elems c*16 + hi*8 + {0..7}.
//   w[0..7] = cvt_pk pairs of p[0..15];  chunk c uses w[4c..4c+3].
// f0 = hi ? sx(w2) : w0 ; f1 = hi ? sx(w3) : w1
// f2 = hi ? w2 : sx(w0) ; f3 = hi ? w3 : sx(w1)      (sx = shfl_xor lane^32)
// ---------------------------------------------------------------------------
__device__ __forceinline__ short8 pfrag_from(const unsigned int* w, int c, int hi) {
    const unsigned int w0 = w[c * 4 + 0], w1 = w[c * 4 + 1];
    const unsigned int w2 = w[c * 4 + 2], w3 = w[c * 4 + 3];
    const unsigned int sx0 = (unsigned int)__shfl_xor((int)w0, 32);
    const unsigned int sx1 = (unsigned int)__shfl_xor((int)w1, 32);
    const unsigned int sx2 = (unsigned int)__shfl_xor((int)w2, 32);
    const unsigned int sx3 = (unsigned int)__shfl_xor((int)w3, 32);
    FragU fu;
    fu.u[0] = hi ? sx2 : w0;
    fu.u[1] = hi ? sx3 : w1;
    fu.u[2] = hi ? w2 : sx0;
    fu.u[3] = hi ? w3 : sx1;
    return fu.s8;
}

// ---------------------------------------------------------------------------
// 4) pass 1: flash attention, fixed max (exp2-domain, M=8) -> out_l + stats
//    1 wave = 32 q-rows, loops all 64 k-tiles of 32. No LDS, no barriers.
// ---------------------------------------------------------------------------
__launch_bounds__(256)
__global__ void attn_pass1(const unsigned short* __restrict__ Qg,
                           const unsigned short* __restrict__ Kg,
                           const unsigned short* __restrict__ Vtg,
                           unsigned short* __restrict__ AOl,
                           float* __restrict__ Mg) {
    const int bh = blockIdx.y;
    const int wv = threadIdx.x >> 6;
    const int lane = threadIdx.x & 63;
    const int l31 = lane & 31;
    const int hi = lane >> 5;
    const int q0 = (blockIdx.x * 4 + wv) * 32;

    const unsigned short* Qb = Qg + (size_t)bh * 2048 * 32;
    const unsigned short* Kb = Kg + (size_t)bh * 2048 * 32;
    const unsigned short* Vb = Vtg + (size_t)bh * 32 * 2048;

    // Q as B-operand: lane = col q, elems d = dc*16 + hi*8 + j  (held all kernel)
    short8 qf0 = *(const short8*)(Qb + (size_t)(q0 + l31) * 32 + hi * 8);
    short8 qf1 = *(const short8*)(Qb + (size_t)(q0 + l31) * 32 + 16 + hi * 8);

    f32x16 acc = {};
    float l_run = 0.f;

    // prefetch tile 0
    short8 kf0 = *(const short8*)(Kb + (size_t)l31 * 32 + hi * 8);
    short8 kf1 = *(const short8*)(Kb + (size_t)l31 * 32 + 16 + hi * 8);
    short8 vf0 = *(const short8*)(Vb + (size_t)l31 * 2048 + hi * 8);
    short8 vf1 = *(const short8*)(Vb + (size_t)l31 * 2048 + 16 + hi * 8);

    for (int kt = 0; kt < 64; ++kt) {
        const short8 ck0 = kf0, ck1 = kf1, cv0 = vf0, cv1 = vf1;
        if (kt < 63) {   // prefetch next tile
            const int kn = (kt + 1) * 32;
            kf0 = *(const short8*)(Kb + (size_t)(kn + l31) * 32 + hi * 8);
            kf1 = *(const short8*)(Kb + (size_t)(kn + l31) * 32 + 16 + hi * 8);
            vf0 = *(const short8*)(Vb + (size_t)l31 * 2048 + kn + hi * 8);
            vf1 = *(const short8*)(Vb + (size_t)l31 * 2048 + kn + 16 + hi * 8);
        }

        // S^T tile: lane holds col q = q0+l31, rows k-local in regs
        f32x16 s = {};
        s = mfma32(ck0, qf0, s);
        s = mfma32(ck1, qf1, s);

        float p[16];
        float rs = 0.f;
#pragma unroll
        for (int j = 0; j < 16; ++j) { p[j] = fexp2(s[j] - 8.0f); rs += p[j]; }
        l_run += rs;

        unsigned int w[8];
#pragma unroll
        for (int m = 0; m < 8; ++m)
            asm("v_cvt_pk_bf16_f32 %0, %1, %2"
                : "=v"(w[m]) : "v"(p[2 * m]), "v"(p[2 * m + 1]));

        // PV: out_l^T[d][q] += V^T[d][k] @ P^T[k][q]
        acc = mfma32(cv0, pfrag_from(w, 0, hi), acc);
        acc = mfma32(cv1, pfrag_from(w, 1, hi), acc);
    }

    const float lsum = l_run + __shfl_xor(l_run, 32);
    const float rl = 1.0f / lsum;
    const int b_ = bh >> 3, h = bh & 7;
    const int q = q0 + l31;
    unsigned short* dst = AOl + (size_t)(b_ * 2048 + q) * 256 + h * 32;
#pragma unroll
    for (int g2 = 0; g2 < 4; ++g2) {
        u16x4 pk = { bf16_rn(acc[4 * g2 + 0] * rl), bf16_rn(acc[4 * g2 + 1] * rl),
                     bf16_rn(acc[4 * g2 + 2] * rl), bf16_rn(acc[4 * g2 + 3] * rl) };
        *(u16x4*)(dst + 8 * g2 + 4 * hi) = pk;
    }
    if (hi == 0) Mg[bh * 2048 + q] = 8.0f + flog2(lsum);
}

// ---------------------------------------------------------------------------
// 5) pass 2: out_r = attn^T @ v. 1 wave = 32 k-rows, loops 64 q-tiles.
//    p = 2^(s - M_q) fully normalized. No LDS, no barriers.
// ---------------------------------------------------------------------------
__launch_bounds__(256)
__global__ void attn_pass2(const unsigned short* __restrict__ Qg,
                           const unsigned short* __restrict__ Kg,
                           const unsigned short* __restrict__ Vtg,
                           const float* __restrict__ Mg,
                           unsigned short* __restrict__ AOr) {
    const int bh = blockIdx.y;
    const int wv = threadIdx.x >> 6;
    const int lane = threadIdx.x & 63;
    const int l31 = lane & 31;
    const int hi = lane >> 5;
    const int k0 = (blockIdx.x * 4 + wv) * 32;

    const unsigned short* Qb = Qg + (size_t)bh * 2048 * 32;
    const unsigned short* Kb = Kg + (size_t)bh * 2048 * 32;
    const unsigned short* Vb = Vtg + (size_t)bh * 32 * 2048;
    const float* Mb = Mg + (size_t)bh * 2048;

    // K as B-operand: lane = col k, elems d (held all kernel)
    short8 kf0 = *(const short8*)(Kb + (size_t)(k0 + l31) * 32 + hi * 8);
    short8 kf1 = *(const short8*)(Kb + (size_t)(k0 + l31) * 32 + 16 + hi * 8);

    f32x16 acc = {};

    // prefetch tile 0
    short8 qa0 = *(const short8*)(Qb + (size_t)l31 * 32 + hi * 8);
    short8 qa1 = *(const short8*)(Qb + (size_t)l31 * 32 + 16 + hi * 8);
    short8 vf0 = *(const short8*)(Vb + (size_t)l31 * 2048 + hi * 8);
    short8 vf1 = *(const short8*)(Vb + (size_t)l31 * 2048 + 16 + hi * 8);

    for (int qt = 0; qt < 64; ++qt) {
        const int qq = qt * 32;
        const short8 cq0 = qa0, cq1 = qa1, cv0 = vf0, cv1 = vf1;
        if (qt < 63) {
            const int qn = qq + 32;
            qa0 = *(const short8*)(Qb + (size_t)(qn + l31) * 32 + hi * 8);
            qa1 = *(const short8*)(Qb + (size_t)(qn + l31) * 32 + 16 + hi * 8);
            vf0 = *(const short8*)(Vb + (size_t)l31 * 2048 + qn + hi * 8);
            vf1 = *(const short8*)(Vb + (size_t)l31 * 2048 + qn + 16 + hi * 8);
        }

        // S tile: lane holds col k = k0+l31, rows q-local in regs
        f32x16 s = {};
        s = mfma32(cq0, kf0, s);
        s = mfma32(cq1, kf1, s);

        float p[16];
#pragma unroll
        for (int j = 0; j < 16; ++j) {
            const int qr = (j & 3) + 8 * (j >> 2) + 4 * hi;
            p[j] = fexp2(s[j] - Mb[qq + qr]);
        }

        unsigned int w[8];
#pragma unroll
        for (int m = 0; m < 8; ++m)
            asm("v_cvt_pk_bf16_f32 %0, %1, %2"
                : "=v"(w[m]) : "v"(p[2 * m]), "v"(p[2 * m + 1]));

        // out_r[k][d] += P^T[k][q] @ V[q][d]
        acc = mfma32(pfrag_from(w, 0, hi), cv0, acc);
        acc = mfma32(pfrag_from(w, 1, hi), cv1, acc);
    }

    const int b_ = bh >> 3, h = bh & 7;
#pragma unroll
    for (int j = 0; j < 16; ++j) {
        const int krow = k0 + (j & 3) + 8 * (j >> 2) + 4 * hi;
        AOr[(size_t)(b_ * 2048 + krow) * 256 + h * 32 + l31] = bf16_rn(acc[j]);
    }
}

// ---------------------------------------------------------------------------
// 6) output projection + LayerNorm + residual (fp32 out)
// ---------------------------------------------------------------------------
__launch_bounds__(256)
__global__ void proj_ln(const unsigned short* __restrict__ AO,
                        const unsigned short* __restrict__ Wpt,
                        const float* __restrict__ bp,
                        const float* __restrict__ gamma, const float* __restrict__ beta,
                        const float* __restrict__ xres,
                        float* __restrict__ out) {
    __shared__ unsigned short At[64][264];
    __shared__ unsigned short Bt[256][40];

    const int tid = threadIdx.x;
    const int lane = tid & 63, wv = tid >> 6;
    const int a = lane & 15, g = lane >> 4;
    const int r0 = blockIdx.x * 64;

    {
        const int row = tid >> 2, seg = (tid & 3) * 64;
        const unsigned short* src = AO + (size_t)(r0 + row) * 256 + seg;
#pragma unroll
        for (int i = 0; i < 8; ++i)
            *(short8*)&At[row][seg + i * 8] = *(const short8*)(src + i * 8);
    }

    const f32x4 fz = {0.f, 0.f, 0.f, 0.f};
    f32x4 acc[16];
#pragma unroll
    for (int cf = 0; cf < 16; ++cf) acc[cf] = fz;

    for (int ks = 0; ks < 8; ++ks) {
        __syncthreads();
        {
            const unsigned short* src = Wpt + (size_t)tid * 256 + ks * 32;
#pragma unroll
            for (int i = 0; i < 4; ++i)
                *(short8*)&Bt[tid][i * 8] = *(const short8*)(src + i * 8);
        }
        __syncthreads();
        const short8 af = *(const short8*)&At[wv * 16 + a][ks * 32 + g * 8];
#pragma unroll
        for (int cf = 0; cf < 16; ++cf) {
            const short8 bfr = *(const short8*)&Bt[cf * 16 + a][g * 8];
            acc[cf] = mfma16(af, bfr, acc[cf]);
        }
    }

    float bb[16], gg[16], be[16];
#pragma unroll
    for (int cf = 0; cf < 16; ++cf) {
        const int c = cf * 16 + a;
        bb[cf] = bp[c]; gg[cf] = gamma[c]; be[cf] = beta[c];
    }
#pragma unroll
    for (int r = 0; r < 4; ++r) {
        float y[16];
        float s1 = 0.f, s2 = 0.f;
#pragma unroll
        for (int cf = 0; cf < 16; ++cf) {
            y[cf] = acc[cf][r] + bb[cf];
            s1 += y[cf];
            s2 += y[cf] * y[cf];
        }
#pragma unroll
        for (int mask = 1; mask <= 8; mask <<= 1) {
            s1 += __shfl_xor(s1, mask);
            s2 += __shfl_xor(s2, mask);
        }
        const float mu = s1 * (1.0f / 256.0f);
        const float var = s2 * (1.0f / 256.0f) - mu * mu;
        const float rstd = rsqrtf(var + 1e-5f);
        const int R = r0 + wv * 16 + g * 4 + r;
#pragma unroll
        for (int cf = 0; cf < 16; ++cf) {
            const int c = cf * 16 + a;
            out[(size_t)R * 256 + c] =
                (y[cf] - mu) * rstd * gg[cf] + be[cf] + xres[(size_t)R * 256 + c];
        }
    }
}

// ---------------------------------------------------------------------------
extern "C" void kernel_launch(void* const* d_in, const int* in_sizes, int n_in,
                              void* d_out, int out_size, void* d_ws, size_t ws_size,
                              hipStream_t stream) {
    const float* x_l  = (const float*)d_in[0];
    const float* x_r  = (const float*)d_in[1];
    const float* Wq   = (const float*)d_in[2];
    const float* bq   = (const float*)d_in[3];
    const float* Wk   = (const float*)d_in[4];
    const float* bk   = (const float*)d_in[5];
    const float* Wv   = (const float*)d_in[6];
    const float* bv   = (const float*)d_in[7];
    const float* Wp   = (const float*)d_in[8];
    const float* bp   = (const float*)d_in[9];
    const float* ln_g = (const float*)d_in[10];
    const float* ln_b = (const float*)d_in[11];
    const float* rn_g = (const float*)d_in[12];
    const float* rn_b = (const float*)d_in[13];

    const size_t SZ_TOK = (size_t)8192 * 256;

    unsigned short* xl_bf = (unsigned short*)d_ws;
    unsigned short* xr_bf = xl_bf + SZ_TOK;
    unsigned short* xd_bf = xr_bf + SZ_TOK;
    unsigned short* Qg    = xd_bf + SZ_TOK;
    unsigned short* Kg    = Qg + SZ_TOK;
    unsigned short* Vtg   = Kg + SZ_TOK;
    unsigned short* Wqt   = Vtg + SZ_TOK;
    unsigned short* Wkt   = Wqt + 65536;
    unsigned short* Wvt   = Wkt + 65536;
    unsigned short* Wpt   = Wvt + 65536;
    float*          Mg    = (float*)(Wpt + 65536);
    unsigned short* AOl   = xl_bf;   // safe: qkv_gemm (last reader) precedes pass1
    unsigned short* AOr   = xr_bf;
    float* out = (float*)d_out;

    prep_x<<<2048, 256, 0, stream>>>(x_l, x_r, xl_bf, xr_bf, xd_bf);
    prep_w<<<1024, 256, 0, stream>>>(Wq, Wk, Wv, Wp, Wqt, Wkt, Wvt, Wpt);
    qkv_gemm<<<dim3(64, 4, 3), 256, 0, stream>>>(xl_bf, xr_bf, xd_bf,
                                                 Wqt, Wkt, Wvt, bq, bk, bv, Qg, Kg, Vtg);
    attn_pass1<<<dim3(16, 32), 256, 0, stream>>>(Qg, Kg, Vtg, AOl, Mg);
    attn_pass2<<<dim3(16, 32), 256, 0, stream>>>(Qg, Kg, Vtg, Mg, AOr);
    proj_ln<<<128, 256, 0, stream>>>(AOl, Wpt, bp, ln_g, ln_b, x_l, out);
    proj_ln<<<128, 256, 0, stream>>>(AOr, Wpt, bp, rn_g, rn_b, x_r, out + SZ_TOK);
}

// Round 3
// 151.041 us; speedup vs baseline: 1.3646x; 1.2622x over previous
//
#include <hip/hip_runtime.h>
#include <math.h>

// ---------------------------------------------------------------------------
// BiMultiHeadAttention fused pipeline (MI355X / gfx950)
//   B=4 N=2048 E=256 H=8 D=32   (bh = B*H = 32 heads total)
//
// Round 3:
//   - attention passes: 8-wave blocks, split-K in-block (2-way) + LDS combine
//   - XCD-aware block swizzle: XCD i owns heads 4i..4i+3 (L2-resident K/V)
//   - no softmax stats in pass2: V pre-scaled by 1/l (scale_v kernel)
//   - no exp-domain shift at all (normalization is shift-invariant)
//   - permlane32_swap builds P fragments in-register (replaces 8x shfl_xor)
// ---------------------------------------------------------------------------

typedef __attribute__((ext_vector_type(8))) short short8;   // 8 bf16 (4 VGPR)
typedef __attribute__((ext_vector_type(4))) float f32x4;
typedef __attribute__((ext_vector_type(16))) float f32x16;
typedef __attribute__((ext_vector_type(4))) unsigned short u16x4;

union FragU { unsigned int u[4]; short8 s8; };

__device__ __forceinline__ unsigned short bf16_rn(float f) {
    union { float f; unsigned int u; } c; c.f = f;
    return (unsigned short)((c.u + 0x7FFFu + ((c.u >> 16) & 1u)) >> 16);
}
__device__ __forceinline__ float b2f(unsigned short u) {
    union { unsigned int i; float f; } c; c.i = ((unsigned int)u) << 16;
    return c.f;
}

#if __has_builtin(__builtin_amdgcn_exp2f)
__device__ __forceinline__ float fexp2(float x) { return __builtin_amdgcn_exp2f(x); }
#else
__device__ __forceinline__ float fexp2(float x) { return exp2f(x); }
#endif

__device__ __forceinline__ f32x4 mfma16(short8 a, short8 b, f32x4 c) {
    return __builtin_amdgcn_mfma_f32_16x16x32_bf16(a, b, c, 0, 0, 0);
}
__device__ __forceinline__ f32x16 mfma32(short8 a, short8 b, f32x16 c) {
    return __builtin_amdgcn_mfma_f32_32x32x16_bf16(a, b, c, 0, 0, 0);
}

// v_permlane32_swap_b32: new_x = {x.lo32lanes, y.lo32lanes-from-other-half},
// i.e. x's high-32-lane values swap with y's low-32-lane values.
__device__ __forceinline__ void plswap(unsigned int& x, unsigned int& y) {
    asm("v_permlane32_swap_b32 %0, %1" : "+v"(x), "+v"(y));
}

// S^T regs (k-local = (j&3)+8*(j>>2)+4*hi) packed as w[m]=(p[2m],p[2m+1]) ->
// one 16-row chunk of an MFMA operand fragment (contract elems hi*8+{0..7}).
// After swap(w0,w2), swap(w1,w3) the four words ARE the fragment.
__device__ __forceinline__ short8 pfrag(unsigned int w0, unsigned int w1,
                                        unsigned int w2, unsigned int w3) {
    plswap(w0, w2);
    plswap(w1, w3);
    FragU fu;
    fu.u[0] = w0; fu.u[1] = w1; fu.u[2] = w2; fu.u[3] = w3;
    return fu.s8;
}

// ---------------------------------------------------------------------------
// 1) f32 -> bf16 conversion of the two streams + their difference
// ---------------------------------------------------------------------------
__global__ void prep_x(const float* __restrict__ xl, const float* __restrict__ xr,
                       unsigned short* __restrict__ xlb, unsigned short* __restrict__ xrb,
                       unsigned short* __restrict__ xdb) {
    const size_t i = ((size_t)blockIdx.x * 256 + threadIdx.x) * 4;
    const float4 A = *(const float4*)(xl + i);
    const float4 Bv = *(const float4*)(xr + i);
    u16x4 pa = { bf16_rn(A.x), bf16_rn(A.y), bf16_rn(A.z), bf16_rn(A.w) };
    u16x4 pb = { bf16_rn(Bv.x), bf16_rn(Bv.y), bf16_rn(Bv.z), bf16_rn(Bv.w) };
    u16x4 pd = { bf16_rn(A.x - Bv.x), bf16_rn(A.y - Bv.y),
                 bf16_rn(A.z - Bv.z), bf16_rn(A.w - Bv.w) };
    *(u16x4*)(xlb + i) = pa;
    *(u16x4*)(xrb + i) = pb;
    *(u16x4*)(xdb + i) = pd;
}

// ---------------------------------------------------------------------------
// 2) transpose + convert the four 256x256 weight matrices: Wt[n][k] = W[k][n]
// ---------------------------------------------------------------------------
__global__ void prep_w(const float* __restrict__ Wq, const float* __restrict__ Wk,
                       const float* __restrict__ Wv, const float* __restrict__ Wp,
                       unsigned short* __restrict__ Wqt, unsigned short* __restrict__ Wkt,
                       unsigned short* __restrict__ Wvt, unsigned short* __restrict__ Wpt) {
    const int gid = blockIdx.x * 256 + threadIdx.x;       // 0 .. 262143
    const int m = gid >> 16;
    const int idx = gid & 65535;
    const int k = idx >> 8, n = idx & 255;
    const float* W = (m == 0) ? Wq : (m == 1) ? Wk : (m == 2) ? Wv : Wp;
    unsigned short* Wt = (m == 0) ? Wqt : (m == 1) ? Wkt : (m == 2) ? Wvt : Wpt;
    Wt[n * 256 + k] = bf16_rn(W[(size_t)k * 256 + n]);
}

// ---------------------------------------------------------------------------
// 3) QKV projection GEMM: [8192,256] x [256,256] + bias, 3 outputs (z-dim)
// ---------------------------------------------------------------------------
__launch_bounds__(256)
__global__ void qkv_gemm(const unsigned short* __restrict__ xlb,
                         const unsigned short* __restrict__ xrb,
                         const unsigned short* __restrict__ xdb,
                         const unsigned short* __restrict__ Wqt,
                         const unsigned short* __restrict__ Wkt,
                         const unsigned short* __restrict__ Wvt,
                         const float* __restrict__ bq, const float* __restrict__ bk,
                         const float* __restrict__ bv,
                         unsigned short* __restrict__ Qg, unsigned short* __restrict__ Kg,
                         unsigned short* __restrict__ Vtg) {
    const int z = blockIdx.z;
    const unsigned short* A  = (z == 0) ? xlb : (z == 1) ? xrb : xdb;
    const unsigned short* Wt = (z == 0) ? Wqt : (z == 1) ? Wkt : Wvt;
    const float* bias        = (z == 0) ? bq  : (z == 1) ? bk  : bv;

    __shared__ unsigned short At[128][40];
    __shared__ unsigned short Bt[64][40];

    const int tid = threadIdx.x;
    const int lane = tid & 63, wv = tid >> 6;
    const int a = lane & 15, g = lane >> 4;
    const int wr = wv >> 1, wc = wv & 1;
    const int r0 = blockIdx.x * 128;
    const int c0 = blockIdx.y * 64;

    const f32x4 fz = {0.f, 0.f, 0.f, 0.f};
    f32x4 acc[4][2];
#pragma unroll
    for (int f = 0; f < 4; ++f)
#pragma unroll
        for (int t = 0; t < 2; ++t) acc[f][t] = fz;

    const int arow = tid >> 1, aoff = (tid & 1) * 16;
    const int brow = tid >> 2, boff = (tid & 3) * 8;

    for (int ks = 0; ks < 8; ++ks) {
        __syncthreads();
        {
            const unsigned short* asrc = A + (size_t)(r0 + arow) * 256 + ks * 32 + aoff;
            *(short8*)&At[arow][aoff]     = *(const short8*)asrc;
            *(short8*)&At[arow][aoff + 8] = *(const short8*)(asrc + 8);
            *(short8*)&Bt[brow][boff] =
                *(const short8*)(Wt + (size_t)(c0 + brow) * 256 + ks * 32 + boff);
        }
        __syncthreads();
        short8 af[4], bfr[2];
#pragma unroll
        for (int f = 0; f < 4; ++f) af[f] = *(const short8*)&At[wr * 64 + f * 16 + a][g * 8];
#pragma unroll
        for (int t = 0; t < 2; ++t) bfr[t] = *(const short8*)&Bt[wc * 32 + t * 16 + a][g * 8];
#pragma unroll
        for (int f = 0; f < 4; ++f)
#pragma unroll
            for (int t = 0; t < 2; ++t) acc[f][t] = mfma16(af[f], bfr[t], acc[f][t]);
    }

    const float scq = 0.17677669529663687f * 1.4426950408889634f;
#pragma unroll
    for (int t = 0; t < 2; ++t) {
        const int C = c0 + wc * 32 + t * 16 + a;
        const float bb = bias[C];
        const int h = C >> 5, d = C & 31;
#pragma unroll
        for (int f = 0; f < 4; ++f) {
            const int Rb = r0 + wr * 64 + f * 16 + g * 4;
            const int b_ = Rb >> 11, n = Rb & 2047;
            const int bhh = b_ * 8 + h;
            float v[4];
#pragma unroll
            for (int r = 0; r < 4; ++r) {
                v[r] = acc[f][t][r] + bb;
                if (z == 0) v[r] *= scq;
            }
            if (z < 2) {
                unsigned short* dst = ((z == 0) ? Qg : Kg) + (size_t)(bhh * 2048 + n) * 32 + d;
#pragma unroll
                for (int r = 0; r < 4; ++r) dst[(size_t)r * 32] = bf16_rn(v[r]);
            } else {
                u16x4 pk = { bf16_rn(v[0]), bf16_rn(v[1]), bf16_rn(v[2]), bf16_rn(v[3]) };
                *(u16x4*)(Vtg + (size_t)(bhh * 32 + d) * 2048 + n) = pk;
            }
        }
    }
}

// ---------------------------------------------------------------------------
// 4) pass 1: flash attention (exp2 domain, NO shift) -> out_l + invl = 1/l
//    8 waves: (qi = wv&3) q-subtile, (z = wv>>2) k-half; LDS combine at end.
//    XCD swizzle: 1-D grid 512, XCD f&7 owns heads 4*(f&7)..+3.
// ---------------------------------------------------------------------------
__launch_bounds__(512, 4)
__global__ void attn_pass1(const unsigned short* __restrict__ Qg,
                           const unsigned short* __restrict__ Kg,
                           const unsigned short* __restrict__ Vtg,
                           unsigned short* __restrict__ AOl,
                           float* __restrict__ invl) {
    __shared__ float accS[4][16][64];   // z=1 partials: [qi][j][lane]
    __shared__ float lsumS[4][64];

    const int f = blockIdx.x;
    const int bh = 4 * (f & 7) + ((f >> 3) >> 4);
    const int qblk = (f >> 3) & 15;
    const int tid = threadIdx.x;
    const int wv = tid >> 6;
    const int qi = wv & 3, z = wv >> 2;
    const int lane = tid & 63, l31 = lane & 31, hi = lane >> 5;
    const int q0 = (qblk * 4 + qi) * 32;

    const unsigned short* Qb = Qg + (size_t)bh * 2048 * 32;
    const unsigned short* Kb = Kg + (size_t)bh * 2048 * 32;
    const unsigned short* Vb = Vtg + (size_t)bh * 32 * 2048;

    const short8 qf0 = *(const short8*)(Qb + (size_t)(q0 + l31) * 32 + hi * 8);
    const short8 qf1 = *(const short8*)(Qb + (size_t)(q0 + l31) * 32 + 16 + hi * 8);

    f32x16 acc = {};
    float l_run = 0.f;

    const int ktbeg = z * 32, ktend = ktbeg + 32;
    short8 kf0 = *(const short8*)(Kb + (size_t)(ktbeg * 32 + l31) * 32 + hi * 8);
    short8 kf1 = *(const short8*)(Kb + (size_t)(ktbeg * 32 + l31) * 32 + 16 + hi * 8);
    short8 vf0 = *(const short8*)(Vb + (size_t)l31 * 2048 + ktbeg * 32 + hi * 8);
    short8 vf1 = *(const short8*)(Vb + (size_t)l31 * 2048 + ktbeg * 32 + 16 + hi * 8);

    for (int kt = ktbeg; kt < ktend; ++kt) {
        const short8 ck0 = kf0, ck1 = kf1, cv0 = vf0, cv1 = vf1;
        if (kt < ktend - 1) {
            const int kn = (kt + 1) * 32;
            kf0 = *(const short8*)(Kb + (size_t)(kn + l31) * 32 + hi * 8);
            kf1 = *(const short8*)(Kb + (size_t)(kn + l31) * 32 + 16 + hi * 8);
            vf0 = *(const short8*)(Vb + (size_t)l31 * 2048 + kn + hi * 8);
            vf1 = *(const short8*)(Vb + (size_t)l31 * 2048 + kn + 16 + hi * 8);
        }

        f32x16 s = {};
        s = mfma32(ck0, qf0, s);
        s = mfma32(ck1, qf1, s);

        float p[16];
#pragma unroll
        for (int j = 0; j < 16; ++j) p[j] = fexp2(s[j]);
        float r0_ = (p[0] + p[1]) + (p[2] + p[3]);
        float r1_ = (p[4] + p[5]) + (p[6] + p[7]);
        float r2_ = (p[8] + p[9]) + (p[10] + p[11]);
        float r3_ = (p[12] + p[13]) + (p[14] + p[15]);
        l_run += (r0_ + r1_) + (r2_ + r3_);

        unsigned int w[8];
#pragma unroll
        for (int m = 0; m < 8; ++m)
            asm("v_cvt_pk_bf16_f32 %0, %1, %2"
                : "=v"(w[m]) : "v"(p[2 * m]), "v"(p[2 * m + 1]));

        acc = mfma32(cv0, pfrag(w[0], w[1], w[2], w[3]), acc);
        acc = mfma32(cv1, pfrag(w[4], w[5], w[6], w[7]), acc);
    }

    float lsum = l_run + __shfl_xor(l_run, 32);

    if (z == 1) {
#pragma unroll
        for (int j = 0; j < 16; ++j) accS[qi][j][lane] = acc[j];
        lsumS[qi][lane] = lsum;
    }
    __syncthreads();
    if (z == 0) {
        lsum += lsumS[qi][lane];
        const float rl = 1.0f / lsum;
#pragma unroll
        for (int j = 0; j < 16; ++j) acc[j] += accS[qi][j][lane];

        const int b_ = bh >> 3, h = bh & 7;
        const int q = q0 + l31;
        unsigned short* dst = AOl + (size_t)(b_ * 2048 + q) * 256 + h * 32;
#pragma unroll
        for (int g2 = 0; g2 < 4; ++g2) {
            u16x4 pk = { bf16_rn(acc[4 * g2 + 0] * rl), bf16_rn(acc[4 * g2 + 1] * rl),
                         bf16_rn(acc[4 * g2 + 2] * rl), bf16_rn(acc[4 * g2 + 3] * rl) };
            *(u16x4*)(dst + 8 * g2 + 4 * hi) = pk;
        }
        if (hi == 0) invl[bh * 2048 + q] = rl;
    }
}

// ---------------------------------------------------------------------------
// 4.5) Vs[d][n] = Vt[d][n] * invl[n]  (fold softmax denominator into V)
// ---------------------------------------------------------------------------
__global__ void scale_v(const unsigned short* __restrict__ Vtg,
                        const float* __restrict__ invl,
                        unsigned short* __restrict__ Vs) {
    const size_t i = ((size_t)blockIdx.x * 256 + threadIdx.x) * 4;
    const int n = (int)(i & 2047);
    const int bh = (int)(i >> 16);
    const u16x4 v = *(const u16x4*)(Vtg + i);
    const float4 il = *(const float4*)(invl + bh * 2048 + n);
    u16x4 o = { bf16_rn(b2f(v.x) * il.x), bf16_rn(b2f(v.y) * il.y),
                bf16_rn(b2f(v.z) * il.z), bf16_rn(b2f(v.w) * il.w) };
    *(u16x4*)(Vs + i) = o;
}

// ---------------------------------------------------------------------------
// 5) pass 2: out_r = exp2(S)^T @ Vs   (fully normalized, no stats)
//    8 waves: (ki = wv&3) k-subtile, (z = wv>>2) q-half; LDS combine.
// ---------------------------------------------------------------------------
__launch_bounds__(512, 4)
__global__ void attn_pass2(const unsigned short* __restrict__ Qg,
                           const unsigned short* __restrict__ Kg,
                           const unsigned short* __restrict__ Vsg,
                           unsigned short* __restrict__ AOr) {
    __shared__ float accS[4][16][64];

    const int f = blockIdx.x;
    const int bh = 4 * (f & 7) + ((f >> 3) >> 4);
    const int kblk = (f >> 3) & 15;
    const int tid = threadIdx.x;
    const int wv = tid >> 6;
    const int ki = wv & 3, z = wv >> 2;
    const int lane = tid & 63, l31 = lane & 31, hi = lane >> 5;
    const int k0 = (kblk * 4 + ki) * 32;

    const unsigned short* Qb = Qg + (size_t)bh * 2048 * 32;
    const unsigned short* Kb = Kg + (size_t)bh * 2048 * 32;
    const unsigned short* Vb = Vsg + (size_t)bh * 32 * 2048;

    const short8 kf0 = *(const short8*)(Kb + (size_t)(k0 + l31) * 32 + hi * 8);
    const short8 kf1 = *(const short8*)(Kb + (size_t)(k0 + l31) * 32 + 16 + hi * 8);

    f32x16 acc = {};

    const int qtbeg = z * 32, qtend = qtbeg + 32;
    short8 qa0 = *(const short8*)(Qb + (size_t)(qtbeg * 32 + l31) * 32 + hi * 8);
    short8 qa1 = *(const short8*)(Qb + (size_t)(qtbeg * 32 + l31) * 32 + 16 + hi * 8);
    short8 vf0 = *(const short8*)(Vb + (size_t)l31 * 2048 + qtbeg * 32 + hi * 8);
    short8 vf1 = *(const short8*)(Vb + (size_t)l31 * 2048 + qtbeg * 32 + 16 + hi * 8);

    for (int qt = qtbeg; qt < qtend; ++qt) {
        const short8 cq0 = qa0, cq1 = qa1, cv0 = vf0, cv1 = vf1;
        if (qt < qtend - 1) {
            const int qn = (qt + 1) * 32;
            qa0 = *(const short8*)(Qb + (size_t)(qn + l31) * 32 + hi * 8);
            qa1 = *(const short8*)(Qb + (size_t)(qn + l31) * 32 + 16 + hi * 8);
            vf0 = *(const short8*)(Vb + (size_t)l31 * 2048 + qn + hi * 8);
            vf1 = *(const short8*)(Vb + (size_t)l31 * 2048 + qn + 16 + hi * 8);
        }

        f32x16 s = {};
        s = mfma32(cq0, kf0, s);
        s = mfma32(cq1, kf1, s);

        float p[16];
#pragma unroll
        for (int j = 0; j < 16; ++j) p[j] = fexp2(s[j]);

        unsigned int w[8];
#pragma unroll
        for (int m = 0; m < 8; ++m)
            asm("v_cvt_pk_bf16_f32 %0, %1, %2"
                : "=v"(w[m]) : "v"(p[2 * m]), "v"(p[2 * m + 1]));

        acc = mfma32(pfrag(w[0], w[1], w[2], w[3]), cv0, acc);
        acc = mfma32(pfrag(w[4], w[5], w[6], w[7]), cv1, acc);
    }

    if (z == 1) {
#pragma unroll
        for (int j = 0; j < 16; ++j) accS[ki][j][lane] = acc[j];
    }
    __syncthreads();
    if (z == 0) {
#pragma unroll
        for (int j = 0; j < 16; ++j) acc[j] += accS[ki][j][lane];

        const int b_ = bh >> 3, h = bh & 7;
#pragma unroll
        for (int j = 0; j < 16; ++j) {
            const int krow = k0 + (j & 3) + 8 * (j >> 2) + 4 * hi;
            AOr[(size_t)(b_ * 2048 + krow) * 256 + h * 32 + l31] = bf16_rn(acc[j]);
        }
    }
}

// ---------------------------------------------------------------------------
// 6) output projection + LayerNorm + residual (fp32 out)
// ---------------------------------------------------------------------------
__launch_bounds__(256)
__global__ void proj_ln(const unsigned short* __restrict__ AO,
                        const unsigned short* __restrict__ Wpt,
                        const float* __restrict__ bp,
                        const float* __restrict__ gamma, const float* __restrict__ beta,
                        const float* __restrict__ xres,
                        float* __restrict__ out) {
    __shared__ unsigned short At[64][264];
    __shared__ unsigned short Bt[256][40];

    const int tid = threadIdx.x;
    const int lane = tid & 63, wv = tid >> 6;
    const int a = lane & 15, g = lane >> 4;
    const int r0 = blockIdx.x * 64;

    {
        const int row = tid >> 2, seg = (tid & 3) * 64;
        const unsigned short* src = AO + (size_t)(r0 + row) * 256 + seg;
#pragma unroll
        for (int i = 0; i < 8; ++i)
            *(short8*)&At[row][seg + i * 8] = *(const short8*)(src + i * 8);
    }

    const f32x4 fz = {0.f, 0.f, 0.f, 0.f};
    f32x4 acc[16];
#pragma unroll
    for (int cf = 0; cf < 16; ++cf) acc[cf] = fz;

    for (int ks = 0; ks < 8; ++ks) {
        __syncthreads();
        {
            const unsigned short* src = Wpt + (size_t)tid * 256 + ks * 32;
#pragma unroll
            for (int i = 0; i < 4; ++i)
                *(short8*)&Bt[tid][i * 8] = *(const short8*)(src + i * 8);
        }
        __syncthreads();
        const short8 af = *(const short8*)&At[wv * 16 + a][ks * 32 + g * 8];
#pragma unroll
        for (int cf = 0; cf < 16; ++cf) {
            const short8 bfr = *(const short8*)&Bt[cf * 16 + a][g * 8];
            acc[cf] = mfma16(af, bfr, acc[cf]);
        }
    }

    float bb[16], gg[16], be[16];
#pragma unroll
    for (int cf = 0; cf < 16; ++cf) {
        const int c = cf * 16 + a;
        bb[cf] = bp[c]; gg[cf] = gamma[c]; be[cf] = beta[c];
    }
#pragma unroll
    for (int r = 0; r < 4; ++r) {
        float y[16];
        float s1 = 0.f, s2 = 0.f;
#pragma unroll
        for (int cf = 0; cf < 16; ++cf) {
            y[cf] = acc[cf][r] + bb[cf];
            s1 += y[cf];
            s2 += y[cf] * y[cf];
        }
#pragma unroll
        for (int mask = 1; mask <= 8; mask <<= 1) {
            s1 += __shfl_xor(s1, mask);
            s2 += __shfl_xor(s2, mask);
        }
        const float mu = s1 * (1.0f / 256.0f);
        const float var = s2 * (1.0f / 256.0f) - mu * mu;
        const float rstd = rsqrtf(var + 1e-5f);
        const int R = r0 + wv * 16 + g * 4 + r;
#pragma unroll
        for (int cf = 0; cf < 16; ++cf) {
            const int c = cf * 16 + a;
            out[(size_t)R * 256 + c] =
                (y[cf] - mu) * rstd * gg[cf] + be[cf] + xres[(size_t)R * 256 + c];
        }
    }
}

// ---------------------------------------------------------------------------
extern "C" void kernel_launch(void* const* d_in, const int* in_sizes, int n_in,
                              void* d_out, int out_size, void* d_ws, size_t ws_size,
                              hipStream_t stream) {
    const float* x_l  = (const float*)d_in[0];
    const float* x_r  = (const float*)d_in[1];
    const float* Wq   = (const float*)d_in[2];
    const float* bq   = (const float*)d_in[3];
    const float* Wk   = (const float*)d_in[4];
    const float* bk   = (const float*)d_in[5];
    const float* Wv   = (const float*)d_in[6];
    const float* bv   = (const float*)d_in[7];
    const float* Wp   = (const float*)d_in[8];
    const float* bp   = (const float*)d_in[9];
    const float* ln_g = (const float*)d_in[10];
    const float* ln_b = (const float*)d_in[11];
    const float* rn_g = (const float*)d_in[12];
    const float* rn_b = (const float*)d_in[13];

    const size_t SZ_TOK = (size_t)8192 * 256;

    unsigned short* xl_bf = (unsigned short*)d_ws;
    unsigned short* xr_bf = xl_bf + SZ_TOK;
    unsigned short* xd_bf = xr_bf + SZ_TOK;
    unsigned short* Qg    = xd_bf + SZ_TOK;
    unsigned short* Kg    = Qg + SZ_TOK;
    unsigned short* Vtg   = Kg + SZ_TOK;
    unsigned short* Wqt   = Vtg + SZ_TOK;
    unsigned short* Wkt   = Wqt + 65536;
    unsigned short* Wvt   = Wkt + 65536;
    unsigned short* Wpt   = Wvt + 65536;
    float*          invl  = (float*)(Wpt + 65536);   // 65536 f32
    unsigned short* AOl   = xl_bf;   // qkv_gemm (last reader of xl) precedes pass1
    unsigned short* AOr   = xr_bf;
    unsigned short* Vs    = xd_bf;   // xd dead after qkv_gemm
    float* out = (float*)d_out;

    prep_x<<<2048, 256, 0, stream>>>(x_l, x_r, xl_bf, xr_bf, xd_bf);
    prep_w<<<1024, 256, 0, stream>>>(Wq, Wk, Wv, Wp, Wqt, Wkt, Wvt, Wpt);
    qkv_gemm<<<dim3(64, 4, 3), 256, 0, stream>>>(xl_bf, xr_bf, xd_bf,
                                                 Wqt, Wkt, Wvt, bq, bk, bv, Qg, Kg, Vtg);
    attn_pass1<<<512, 512, 0, stream>>>(Qg, Kg, Vtg, AOl, invl);
    scale_v<<<2048, 256, 0, stream>>>(Vtg, invl, Vs);
    attn_pass2<<<512, 512, 0, stream>>>(Qg, Kg, Vs, AOr);
    proj_ln<<<128, 256, 0, stream>>>(AOl, Wpt, bp, ln_g, ln_b, x_l, out);
    proj_ln<<<128, 256, 0, stream>>>(AOr, Wpt, bp, rn_g, rn_b, x_r, out + SZ_TOK);
}

// Round 4
// 104.239 us; speedup vs baseline: 1.9774x; 1.4490x over previous
//
#include <hip/hip_runtime.h>
#include <math.h>

// ---------------------------------------------------------------------------
// BiMultiHeadAttention fused pipeline (MI355X / gfx950)
//   B=4 N=2048 E=256 H=8 D=32   (bh = B*H = 32 heads total)
//
// Round 4:
//   - attn passes: cooperative LDS staging (fragment-major layout), dbuf,
//     1 barrier/iter. Each wave stages 1KB/tile; 4 waves/z share tiles.
//   - scale_v folded into pass1 epilogue (idle z=1 waves scale V by 1/l)
//   - XCD-aware head mapping kept (FETCH dropped 35.9->6.2 MB last round)
// ---------------------------------------------------------------------------

typedef __attribute__((ext_vector_type(8))) short short8;   // 8 bf16 (4 VGPR)
typedef __attribute__((ext_vector_type(4))) float f32x4;
typedef __attribute__((ext_vector_type(16))) float f32x16;
typedef __attribute__((ext_vector_type(4))) unsigned short u16x4;

union FragU { unsigned int u[4]; short8 s8; };

__device__ __forceinline__ unsigned short bf16_rn(float f) {
    union { float f; unsigned int u; } c; c.f = f;
    return (unsigned short)((c.u + 0x7FFFu + ((c.u >> 16) & 1u)) >> 16);
}
__device__ __forceinline__ float b2f(unsigned short u) {
    union { unsigned int i; float f; } c; c.i = ((unsigned int)u) << 16;
    return c.f;
}

#if __has_builtin(__builtin_amdgcn_exp2f)
__device__ __forceinline__ float fexp2(float x) { return __builtin_amdgcn_exp2f(x); }
#else
__device__ __forceinline__ float fexp2(float x) { return exp2f(x); }
#endif

__device__ __forceinline__ f32x4 mfma16(short8 a, short8 b, f32x4 c) {
    return __builtin_amdgcn_mfma_f32_16x16x32_bf16(a, b, c, 0, 0, 0);
}
__device__ __forceinline__ f32x16 mfma32(short8 a, short8 b, f32x16 c) {
    return __builtin_amdgcn_mfma_f32_32x32x16_bf16(a, b, c, 0, 0, 0);
}

__device__ __forceinline__ void plswap(unsigned int& x, unsigned int& y) {
    asm("v_permlane32_swap_b32 %0, %1" : "+v"(x), "+v"(y));
}

// S^T regs (k-local = (j&3)+8*(j>>2)+4*hi) packed as w[m]=(p[2m],p[2m+1]) ->
// one 16-row chunk of an MFMA operand fragment (contract elems hi*8+{0..7}).
__device__ __forceinline__ short8 pfrag(unsigned int w0, unsigned int w1,
                                        unsigned int w2, unsigned int w3) {
    plswap(w0, w2);
    plswap(w1, w3);
    FragU fu;
    fu.u[0] = w0; fu.u[1] = w1; fu.u[2] = w2; fu.u[3] = w3;
    return fu.s8;
}

// ---------------------------------------------------------------------------
// 1) f32 -> bf16 conversion of the two streams + their difference
// ---------------------------------------------------------------------------
__global__ void prep_x(const float* __restrict__ xl, const float* __restrict__ xr,
                       unsigned short* __restrict__ xlb, unsigned short* __restrict__ xrb,
                       unsigned short* __restrict__ xdb) {
    const size_t i = ((size_t)blockIdx.x * 256 + threadIdx.x) * 4;
    const float4 A = *(const float4*)(xl + i);
    const float4 Bv = *(const float4*)(xr + i);
    u16x4 pa = { bf16_rn(A.x), bf16_rn(A.y), bf16_rn(A.z), bf16_rn(A.w) };
    u16x4 pb = { bf16_rn(Bv.x), bf16_rn(Bv.y), bf16_rn(Bv.z), bf16_rn(Bv.w) };
    u16x4 pd = { bf16_rn(A.x - Bv.x), bf16_rn(A.y - Bv.y),
                 bf16_rn(A.z - Bv.z), bf16_rn(A.w - Bv.w) };
    *(u16x4*)(xlb + i) = pa;
    *(u16x4*)(xrb + i) = pb;
    *(u16x4*)(xdb + i) = pd;
}

// ---------------------------------------------------------------------------
// 2) transpose + convert the four 256x256 weight matrices: Wt[n][k] = W[k][n]
// ---------------------------------------------------------------------------
__global__ void prep_w(const float* __restrict__ Wq, const float* __restrict__ Wk,
                       const float* __restrict__ Wv, const float* __restrict__ Wp,
                       unsigned short* __restrict__ Wqt, unsigned short* __restrict__ Wkt,
                       unsigned short* __restrict__ Wvt, unsigned short* __restrict__ Wpt) {
    const int gid = blockIdx.x * 256 + threadIdx.x;       // 0 .. 262143
    const int m = gid >> 16;
    const int idx = gid & 65535;
    const int k = idx >> 8, n = idx & 255;
    const float* W = (m == 0) ? Wq : (m == 1) ? Wk : (m == 2) ? Wv : Wp;
    unsigned short* Wt = (m == 0) ? Wqt : (m == 1) ? Wkt : (m == 2) ? Wvt : Wpt;
    Wt[n * 256 + k] = bf16_rn(W[(size_t)k * 256 + n]);
}

// ---------------------------------------------------------------------------
// 3) QKV projection GEMM: [8192,256] x [256,256] + bias, 3 outputs (z-dim)
// ---------------------------------------------------------------------------
__launch_bounds__(256)
__global__ void qkv_gemm(const unsigned short* __restrict__ xlb,
                         const unsigned short* __restrict__ xrb,
                         const unsigned short* __restrict__ xdb,
                         const unsigned short* __restrict__ Wqt,
                         const unsigned short* __restrict__ Wkt,
                         const unsigned short* __restrict__ Wvt,
                         const float* __restrict__ bq, const float* __restrict__ bk,
                         const float* __restrict__ bv,
                         unsigned short* __restrict__ Qg, unsigned short* __restrict__ Kg,
                         unsigned short* __restrict__ Vtg) {
    const int z = blockIdx.z;
    const unsigned short* A  = (z == 0) ? xlb : (z == 1) ? xrb : xdb;
    const unsigned short* Wt = (z == 0) ? Wqt : (z == 1) ? Wkt : Wvt;
    const float* bias        = (z == 0) ? bq  : (z == 1) ? bk  : bv;

    __shared__ unsigned short At[128][40];
    __shared__ unsigned short Bt[64][40];

    const int tid = threadIdx.x;
    const int lane = tid & 63, wv = tid >> 6;
    const int a = lane & 15, g = lane >> 4;
    const int wr = wv >> 1, wc = wv & 1;
    const int r0 = blockIdx.x * 128;
    const int c0 = blockIdx.y * 64;

    const f32x4 fz = {0.f, 0.f, 0.f, 0.f};
    f32x4 acc[4][2];
#pragma unroll
    for (int f = 0; f < 4; ++f)
#pragma unroll
        for (int t = 0; t < 2; ++t) acc[f][t] = fz;

    const int arow = tid >> 1, aoff = (tid & 1) * 16;
    const int brow = tid >> 2, boff = (tid & 3) * 8;

    for (int ks = 0; ks < 8; ++ks) {
        __syncthreads();
        {
            const unsigned short* asrc = A + (size_t)(r0 + arow) * 256 + ks * 32 + aoff;
            *(short8*)&At[arow][aoff]     = *(const short8*)asrc;
            *(short8*)&At[arow][aoff + 8] = *(const short8*)(asrc + 8);
            *(short8*)&Bt[brow][boff] =
                *(const short8*)(Wt + (size_t)(c0 + brow) * 256 + ks * 32 + boff);
        }
        __syncthreads();
        short8 af[4], bfr[2];
#pragma unroll
        for (int f = 0; f < 4; ++f) af[f] = *(const short8*)&At[wr * 64 + f * 16 + a][g * 8];
#pragma unroll
        for (int t = 0; t < 2; ++t) bfr[t] = *(const short8*)&Bt[wc * 32 + t * 16 + a][g * 8];
#pragma unroll
        for (int f = 0; f < 4; ++f)
#pragma unroll
            for (int t = 0; t < 2; ++t) acc[f][t] = mfma16(af[f], bfr[t], acc[f][t]);
    }

    const float scq = 0.17677669529663687f * 1.4426950408889634f;
#pragma unroll
    for (int t = 0; t < 2; ++t) {
        const int C = c0 + wc * 32 + t * 16 + a;
        const float bb = bias[C];
        const int h = C >> 5, d = C & 31;
#pragma unroll
        for (int f = 0; f < 4; ++f) {
            const int Rb = r0 + wr * 64 + f * 16 + g * 4;
            const int b_ = Rb >> 11, n = Rb & 2047;
            const int bhh = b_ * 8 + h;
            float v[4];
#pragma unroll
            for (int r = 0; r < 4; ++r) {
                v[r] = acc[f][t][r] + bb;
                if (z == 0) v[r] *= scq;
            }
            if (z < 2) {
                unsigned short* dst = ((z == 0) ? Qg : Kg) + (size_t)(bhh * 2048 + n) * 32 + d;
#pragma unroll
                for (int r = 0; r < 4; ++r) dst[(size_t)r * 32] = bf16_rn(v[r]);
            } else {
                u16x4 pk = { bf16_rn(v[0]), bf16_rn(v[1]), bf16_rn(v[2]), bf16_rn(v[3]) };
                *(u16x4*)(Vtg + (size_t)(bhh * 32 + d) * 2048 + n) = pk;
            }
        }
    }
}

// ---------------------------------------------------------------------------
// 4) pass 1: flash attention (exp2 domain, no shift) -> out_l + Vs = V/l
//    8 waves: qi (q-subtile 0..3), z (k-half 0..1). Fragment-major LDS
//    staging: ST[z][buf][kv][c][slot][8], 16B chunk == one fragment entry.
// ---------------------------------------------------------------------------
#define P1_STEP(T, CUR)                                                         \
    {                                                                           \
        if ((T) < 31) *(short8*)((CUR) ? sd0 : sd1) = rr;                       \
        if ((T) < 30) rr = *(const short8*)(sgb + (size_t)(z * 32 + (T) + 2) * gstep); \
        const unsigned short* sb = (CUR) ? stz1 : stz0;                         \
        const short8 ck0 = *(const short8*)(sb + ro);                           \
        const short8 ck1 = *(const short8*)(sb + 512 + ro);                     \
        const short8 cv0 = *(const short8*)(sb + 1024 + ro);                    \
        const short8 cv1 = *(const short8*)(sb + 1536 + ro);                    \
        f32x16 s = {};                                                          \
        s = mfma32(ck0, qf0, s);                                                \
        s = mfma32(ck1, qf1, s);                                                \
        float p[16];                                                            \
        _Pragma("unroll") for (int j = 0; j < 16; ++j) p[j] = fexp2(s[j]);      \
        l_run += ((p[0] + p[1]) + (p[2] + p[3])) + ((p[4] + p[5]) + (p[6] + p[7])) \
               + ((p[8] + p[9]) + (p[10] + p[11])) + ((p[12] + p[13]) + (p[14] + p[15])); \
        unsigned int w[8];                                                      \
        _Pragma("unroll") for (int mm = 0; mm < 8; ++mm)                        \
            asm("v_cvt_pk_bf16_f32 %0, %1, %2"                                  \
                : "=v"(w[mm]) : "v"(p[2 * mm]), "v"(p[2 * mm + 1]));            \
        acc = mfma32(cv0, pfrag(w[0], w[1], w[2], w[3]), acc);                  \
        acc = mfma32(cv1, pfrag(w[4], w[5], w[6], w[7]), acc);                  \
        __syncthreads();                                                        \
    }

__launch_bounds__(512, 4)
__global__ void attn_pass1(const unsigned short* __restrict__ Qg,
                           const unsigned short* __restrict__ Kg,
                           const unsigned short* __restrict__ Vtg,
                           unsigned short* __restrict__ AOl,
                           unsigned short* __restrict__ Vsg) {
    __shared__ unsigned short ST[2][2][2][2][64][8];   // [z][buf][kv][c][slot][e] 16KB
    __shared__ float accS[4][16][64];                  // 16KB
    __shared__ float lsumS[4][64];                     // 1KB (then rl broadcast)

    const int f = blockIdx.x;
    const int bh = 4 * (f & 7) + (f >> 7);
    const int qblk = (f >> 3) & 15;
    const int tid = threadIdx.x;
    const int wv = tid >> 6;
    const int qi = wv & 3, z = wv >> 2;
    const int lane = tid & 63, l31 = lane & 31, hi = lane >> 5;
    const int q0 = qblk * 128 + qi * 32;

    const unsigned short* Qb = Qg + (size_t)bh * 2048 * 32;
    const unsigned short* Kb = Kg + (size_t)bh * 2048 * 32;
    const unsigned short* Vb = Vtg + (size_t)bh * 32 * 2048;

    const short8 qf0 = *(const short8*)(Qb + (size_t)(q0 + l31) * 32 + hi * 8);
    const short8 qf1 = *(const short8*)(Qb + (size_t)(q0 + l31) * 32 + 16 + hi * 8);

    // staging geometry: qi<2 -> K rows, qi>=2 -> V rows (16 rows per wave)
    const int kv = qi >> 1;
    const int srow = (qi & 1) * 16 + (lane >> 2);
    const int m = lane & 3;
    unsigned short* sd0 = &ST[z][0][kv][m >> 1][srow + 32 * (m & 1)][0];
    unsigned short* sd1 = &ST[z][1][kv][m >> 1][srow + 32 * (m & 1)][0];
    const size_t gstep = kv ? 32 : 1024;               // per-tile element step
    const unsigned short* sgb = kv
        ? Vb + (size_t)srow * 2048 + m * 8
        : Kb + (size_t)srow * 32 + m * 8;

    const unsigned short* stz0 = &ST[z][0][0][0][0][0];
    const unsigned short* stz1 = &ST[z][1][0][0][0][0];
    const int ro = (l31 + 32 * hi) * 8;

    f32x16 acc = {};
    float l_run = 0.f;

    // prologue: tile0 -> buf0, tile1 -> regs
    short8 rr = *(const short8*)(sgb + (size_t)(z * 32) * gstep);
    *(short8*)sd0 = rr;
    rr = *(const short8*)(sgb + (size_t)(z * 32 + 1) * gstep);
    __syncthreads();

    for (int tt = 0; tt < 16; ++tt) {
        P1_STEP(2 * tt, 0)
        P1_STEP(2 * tt + 1, 1)
    }

    float lsum = l_run + __shfl_xor(l_run, 32);

    if (z == 1) {
#pragma unroll
        for (int j = 0; j < 16; ++j) accS[qi][j][lane] = acc[j];
        lsumS[qi][lane] = lsum;
    }
    __syncthreads();
    if (z == 0) {
        lsum += lsumS[qi][lane];
        const float rl = 1.0f / lsum;
#pragma unroll
        for (int j = 0; j < 16; ++j) acc[j] += accS[qi][j][lane];

        const int b_ = bh >> 3, h = bh & 7;
        const int q = q0 + l31;
        unsigned short* dst = AOl + (size_t)(b_ * 2048 + q) * 256 + h * 32;
#pragma unroll
        for (int g2 = 0; g2 < 4; ++g2) {
            u16x4 pk = { bf16_rn(acc[4 * g2 + 0] * rl), bf16_rn(acc[4 * g2 + 1] * rl),
                         bf16_rn(acc[4 * g2 + 2] * rl), bf16_rn(acc[4 * g2 + 3] * rl) };
            *(u16x4*)(dst + 8 * g2 + 4 * hi) = pk;
        }
        if (hi == 0) lsumS[qi][l31] = rl;   // rl for column q0+l31
    }
    __syncthreads();
    if (z == 1) {
        // scale V columns [q0, q0+32) by rl: lane (l31,hi) -> d=l31, 16 cols
        const int cb = hi * 16;
        float il[16];
#pragma unroll
        for (int e = 0; e < 16; e += 4) {
            const float4 v4 = *(const float4*)&lsumS[qi][cb + e];
            il[e] = v4.x; il[e + 1] = v4.y; il[e + 2] = v4.z; il[e + 3] = v4.w;
        }
        const unsigned short* vsrc = Vb + (size_t)l31 * 2048 + q0 + cb;
        unsigned short* vdst = Vsg + (size_t)bh * 32 * 2048 + (size_t)l31 * 2048 + q0 + cb;
#pragma unroll
        for (int c4 = 0; c4 < 4; ++c4) {
            const u16x4 vv = *(const u16x4*)(vsrc + c4 * 4);
            u16x4 o = { bf16_rn(b2f(vv.x) * il[c4 * 4 + 0]),
                        bf16_rn(b2f(vv.y) * il[c4 * 4 + 1]),
                        bf16_rn(b2f(vv.z) * il[c4 * 4 + 2]),
                        bf16_rn(b2f(vv.w) * il[c4 * 4 + 3]) };
            *(u16x4*)(vdst + c4 * 4) = o;
        }
    }
}

// ---------------------------------------------------------------------------
// 5) pass 2: out_r = exp2(S)^T @ Vs  (Vs pre-normalized). Same staging.
//    8 waves: ki (k-subtile 0..3), z (q-half 0..1).
// ---------------------------------------------------------------------------
#define P2_STEP(T, CUR)                                                         \
    {                                                                           \
        if ((T) < 31) *(short8*)((CUR) ? sd0 : sd1) = rr;                       \
        if ((T) < 30) rr = *(const short8*)(sgb + (size_t)(z * 32 + (T) + 2) * gstep); \
        const unsigned short* sb = (CUR) ? stz1 : stz0;                         \
        const short8 cq0 = *(const short8*)(sb + ro);                           \
        const short8 cq1 = *(const short8*)(sb + 512 + ro);                     \
        const short8 cv0 = *(const short8*)(sb + 1024 + ro);                    \
        const short8 cv1 = *(const short8*)(sb + 1536 + ro);                    \
        f32x16 s = {};                                                          \
        s = mfma32(cq0, kf0, s);                                                \
        s = mfma32(cq1, kf1, s);                                                \
        float p[16];                                                            \
        _Pragma("unroll") for (int j = 0; j < 16; ++j) p[j] = fexp2(s[j]);      \
        unsigned int w[8];                                                      \
        _Pragma("unroll") for (int mm = 0; mm < 8; ++mm)                        \
            asm("v_cvt_pk_bf16_f32 %0, %1, %2"                                  \
                : "=v"(w[mm]) : "v"(p[2 * mm]), "v"(p[2 * mm + 1]));            \
        acc = mfma32(pfrag(w[0], w[1], w[2], w[3]), cv0, acc);                  \
        acc = mfma32(pfrag(w[4], w[5], w[6], w[7]), cv1, acc);                  \
        __syncthreads();                                                        \
    }

__launch_bounds__(512, 4)
__global__ void attn_pass2(const unsigned short* __restrict__ Qg,
                           const unsigned short* __restrict__ Kg,
                           const unsigned short* __restrict__ Vsg,
                           unsigned short* __restrict__ AOr) {
    __shared__ unsigned short ST[2][2][2][2][64][8];   // [z][buf][kv][c][slot][e]
    __shared__ float accS[4][16][64];

    const int f = blockIdx.x;
    const int bh = 4 * (f & 7) + (f >> 7);
    const int kblk = (f >> 3) & 15;
    const int tid = threadIdx.x;
    const int wv = tid >> 6;
    const int ki = wv & 3, z = wv >> 2;
    const int lane = tid & 63, l31 = lane & 31, hi = lane >> 5;
    const int k0 = kblk * 128 + ki * 32;

    const unsigned short* Qb = Qg + (size_t)bh * 2048 * 32;
    const unsigned short* Kb = Kg + (size_t)bh * 2048 * 32;
    const unsigned short* Vb = Vsg + (size_t)bh * 32 * 2048;

    const short8 kf0 = *(const short8*)(Kb + (size_t)(k0 + l31) * 32 + hi * 8);
    const short8 kf1 = *(const short8*)(Kb + (size_t)(k0 + l31) * 32 + 16 + hi * 8);

    const int kv = ki >> 1;
    const int srow = (ki & 1) * 16 + (lane >> 2);
    const int m = lane & 3;
    unsigned short* sd0 = &ST[z][0][kv][m >> 1][srow + 32 * (m & 1)][0];
    unsigned short* sd1 = &ST[z][1][kv][m >> 1][srow + 32 * (m & 1)][0];
    const size_t gstep = kv ? 32 : 1024;
    const unsigned short* sgb = kv
        ? Vb + (size_t)srow * 2048 + m * 8
        : Qb + (size_t)srow * 32 + m * 8;

    const unsigned short* stz0 = &ST[z][0][0][0][0][0];
    const unsigned short* stz1 = &ST[z][1][0][0][0][0];
    const int ro = (l31 + 32 * hi) * 8;

    f32x16 acc = {};

    short8 rr = *(const short8*)(sgb + (size_t)(z * 32) * gstep);
    *(short8*)sd0 = rr;
    rr = *(const short8*)(sgb + (size_t)(z * 32 + 1) * gstep);
    __syncthreads();

    for (int tt = 0; tt < 16; ++tt) {
        P2_STEP(2 * tt, 0)
        P2_STEP(2 * tt + 1, 1)
    }

    if (z == 1) {
#pragma unroll
        for (int j = 0; j < 16; ++j) accS[ki][j][lane] = acc[j];
    }
    __syncthreads();
    if (z == 0) {
#pragma unroll
        for (int j = 0; j < 16; ++j) acc[j] += accS[ki][j][lane];

        const int b_ = bh >> 3, h = bh & 7;
#pragma unroll
        for (int j = 0; j < 16; ++j) {
            const int krow = k0 + (j & 3) + 8 * (j >> 2) + 4 * hi;
            AOr[(size_t)(b_ * 2048 + krow) * 256 + h * 32 + l31] = bf16_rn(acc[j]);
        }
    }
}

// ---------------------------------------------------------------------------
// 6) output projection + LayerNorm + residual (fp32 out)
// ---------------------------------------------------------------------------
__launch_bounds__(256)
__global__ void proj_ln(const unsigned short* __restrict__ AO,
                        const unsigned short* __restrict__ Wpt,
                        const float* __restrict__ bp,
                        const float* __restrict__ gamma, const float* __restrict__ beta,
                        const float* __restrict__ xres,
                        float* __restrict__ out) {
    __shared__ unsigned short At[64][264];
    __shared__ unsigned short Bt[256][40];

    const int tid = threadIdx.x;
    const int lane = tid & 63, wv = tid >> 6;
    const int a = lane & 15, g = lane >> 4;
    const int r0 = blockIdx.x * 64;

    {
        const int row = tid >> 2, seg = (tid & 3) * 64;
        const unsigned short* src = AO + (size_t)(r0 + row) * 256 + seg;
#pragma unroll
        for (int i = 0; i < 8; ++i)
            *(short8*)&At[row][seg + i * 8] = *(const short8*)(src + i * 8);
    }

    const f32x4 fz = {0.f, 0.f, 0.f, 0.f};
    f32x4 acc[16];
#pragma unroll
    for (int cf = 0; cf < 16; ++cf) acc[cf] = fz;

    for (int ks = 0; ks < 8; ++ks) {
        __syncthreads();
        {
            const unsigned short* src = Wpt + (size_t)tid * 256 + ks * 32;
#pragma unroll
            for (int i = 0; i < 4; ++i)
                *(short8*)&Bt[tid][i * 8] = *(const short8*)(src + i * 8);
        }
        __syncthreads();
        const short8 af = *(const short8*)&At[wv * 16 + a][ks * 32 + g * 8];
#pragma unroll
        for (int cf = 0; cf < 16; ++cf) {
            const short8 bfr = *(const short8*)&Bt[cf * 16 + a][g * 8];
            acc[cf] = mfma16(af, bfr, acc[cf]);
        }
    }

    float bb[16], gg[16], be[16];
#pragma unroll
    for (int cf = 0; cf < 16; ++cf) {
        const int c = cf * 16 + a;
        bb[cf] = bp[c]; gg[cf] = gamma[c]; be[cf] = beta[c];
    }
#pragma unroll
    for (int r = 0; r < 4; ++r) {
        float y[16];
        float s1 = 0.f, s2 = 0.f;
#pragma unroll
        for (int cf = 0; cf < 16; ++cf) {
            y[cf] = acc[cf][r] + bb[cf];
            s1 += y[cf];
            s2 += y[cf] * y[cf];
        }
#pragma unroll
        for (int mask = 1; mask <= 8; mask <<= 1) {
            s1 += __shfl_xor(s1, mask);
            s2 += __shfl_xor(s2, mask);
        }
        const float mu = s1 * (1.0f / 256.0f);
        const float var = s2 * (1.0f / 256.0f) - mu * mu;
        const float rstd = rsqrtf(var + 1e-5f);
        const int R = r0 + wv * 16 + g * 4 + r;
#pragma unroll
        for (int cf = 0; cf < 16; ++cf) {
            const int c = cf * 16 + a;
            out[(size_t)R * 256 + c] =
                (y[cf] - mu) * rstd * gg[cf] + be[cf] + xres[(size_t)R * 256 + c];
        }
    }
}

// ---------------------------------------------------------------------------
extern "C" void kernel_launch(void* const* d_in, const int* in_sizes, int n_in,
                              void* d_out, int out_size, void* d_ws, size_t ws_size,
                              hipStream_t stream) {
    const float* x_l  = (const float*)d_in[0];
    const float* x_r  = (const float*)d_in[1];
    const float* Wq   = (const float*)d_in[2];
    const float* bq   = (const float*)d_in[3];
    const float* Wk   = (const float*)d_in[4];
    const float* bk   = (const float*)d_in[5];
    const float* Wv   = (const float*)d_in[6];
    const float* bv   = (const float*)d_in[7];
    const float* Wp   = (const float*)d_in[8];
    const float* bp   = (const float*)d_in[9];
    const float* ln_g = (const float*)d_in[10];
    const float* ln_b = (const float*)d_in[11];
    const float* rn_g = (const float*)d_in[12];
    const float* rn_b = (const float*)d_in[13];

    const size_t SZ_TOK = (size_t)8192 * 256;

    unsigned short* xl_bf = (unsigned short*)d_ws;
    unsigned short* xr_bf = xl_bf + SZ_TOK;
    unsigned short* xd_bf = xr_bf + SZ_TOK;
    unsigned short* Qg    = xd_bf + SZ_TOK;
    unsigned short* Kg    = Qg + SZ_TOK;
    unsigned short* Vtg   = Kg + SZ_TOK;
    unsigned short* Wqt   = Vtg + SZ_TOK;
    unsigned short* Wkt   = Wqt + 65536;
    unsigned short* Wvt   = Wkt + 65536;
    unsigned short* Wpt   = Wvt + 65536;
    unsigned short* AOl   = xl_bf;   // qkv_gemm (last reader of xl) precedes pass1
    unsigned short* AOr   = xr_bf;
    unsigned short* Vs    = xd_bf;   // xd dead after qkv_gemm
    float* out = (float*)d_out;

    prep_x<<<2048, 256, 0, stream>>>(x_l, x_r, xl_bf, xr_bf, xd_bf);
    prep_w<<<1024, 256, 0, stream>>>(Wq, Wk, Wv, Wp, Wqt, Wkt, Wvt, Wpt);
    qkv_gemm<<<dim3(64, 4, 3), 256, 0, stream>>>(xl_bf, xr_bf, xd_bf,
                                                 Wqt, Wkt, Wvt, bq, bk, bv, Qg, Kg, Vtg);
    attn_pass1<<<512, 512, 0, stream>>>(Qg, Kg, Vtg, AOl, Vs);
    attn_pass2<<<512, 512, 0, stream>>>(Qg, Kg, Vs, AOr);
    proj_ln<<<128, 256, 0, stream>>>(AOl, Wpt, bp, ln_g, ln_b, x_l, out);
    proj_ln<<<128, 256, 0, stream>>>(AOr, Wpt, bp, rn_g, rn_b, x_r, out + SZ_TOK);
}

// Round 5
// 90.371 us; speedup vs baseline: 2.2808x; 1.1534x over previous
//
#include <hip/hip_runtime.h>
#include <math.h>

// ---------------------------------------------------------------------------
// BiMultiHeadAttention fused pipeline (MI355X / gfx950)
//   B=4 N=2048 E=256 H=8 D=32   (bh = B*H = 32 heads total)
//
// Round 5:
//   - attn passes: 64-k phases (2 tiles/phase, 4 LDS tile buffers) -> half
//     the barriers; 2 staged loads in flight
//   - proj_ln: L/R fused in one launch (grid 128x2 = full GPU), Bt dbuf
//     (1 barrier/ks)
//   - prep_x + prep_w merged into one launch; qkv dbuf (1 barrier/ks)
// ---------------------------------------------------------------------------

typedef __attribute__((ext_vector_type(8))) short short8;   // 8 bf16 (4 VGPR)
typedef __attribute__((ext_vector_type(4))) float f32x4;
typedef __attribute__((ext_vector_type(16))) float f32x16;
typedef __attribute__((ext_vector_type(4))) unsigned short u16x4;

union FragU { unsigned int u[4]; short8 s8; };

__device__ __forceinline__ unsigned short bf16_rn(float f) {
    union { float f; unsigned int u; } c; c.f = f;
    return (unsigned short)((c.u + 0x7FFFu + ((c.u >> 16) & 1u)) >> 16);
}
__device__ __forceinline__ float b2f(unsigned short u) {
    union { unsigned int i; float f; } c; c.i = ((unsigned int)u) << 16;
    return c.f;
}

#if __has_builtin(__builtin_amdgcn_exp2f)
__device__ __forceinline__ float fexp2(float x) { return __builtin_amdgcn_exp2f(x); }
#else
__device__ __forceinline__ float fexp2(float x) { return exp2f(x); }
#endif

__device__ __forceinline__ f32x4 mfma16(short8 a, short8 b, f32x4 c) {
    return __builtin_amdgcn_mfma_f32_16x16x32_bf16(a, b, c, 0, 0, 0);
}
__device__ __forceinline__ f32x16 mfma32(short8 a, short8 b, f32x16 c) {
    return __builtin_amdgcn_mfma_f32_32x32x16_bf16(a, b, c, 0, 0, 0);
}

__device__ __forceinline__ void plswap(unsigned int& x, unsigned int& y) {
    asm("v_permlane32_swap_b32 %0, %1" : "+v"(x), "+v"(y));
}

// S^T regs (k-local = (j&3)+8*(j>>2)+4*hi) packed as w[m]=(p[2m],p[2m+1]) ->
// one 16-row chunk of an MFMA operand fragment (contract elems hi*8+{0..7}).
__device__ __forceinline__ short8 pfrag(unsigned int w0, unsigned int w1,
                                        unsigned int w2, unsigned int w3) {
    plswap(w0, w2);
    plswap(w1, w3);
    FragU fu;
    fu.u[0] = w0; fu.u[1] = w1; fu.u[2] = w2; fu.u[3] = w3;
    return fu.s8;
}

// ---------------------------------------------------------------------------
// 1) merged prep: blocks [0,2048) convert x streams; [2048,3072) transpose W
// ---------------------------------------------------------------------------
__global__ void prep_all(const float* __restrict__ xl, const float* __restrict__ xr,
                         const float* __restrict__ Wq, const float* __restrict__ Wk,
                         const float* __restrict__ Wv, const float* __restrict__ Wp,
                         unsigned short* __restrict__ xlb, unsigned short* __restrict__ xrb,
                         unsigned short* __restrict__ xdb,
                         unsigned short* __restrict__ Wqt, unsigned short* __restrict__ Wkt,
                         unsigned short* __restrict__ Wvt, unsigned short* __restrict__ Wpt) {
    const int bid = blockIdx.x;
    if (bid < 2048) {
        const size_t i = ((size_t)bid * 256 + threadIdx.x) * 4;
        const float4 A = *(const float4*)(xl + i);
        const float4 Bv = *(const float4*)(xr + i);
        u16x4 pa = { bf16_rn(A.x), bf16_rn(A.y), bf16_rn(A.z), bf16_rn(A.w) };
        u16x4 pb = { bf16_rn(Bv.x), bf16_rn(Bv.y), bf16_rn(Bv.z), bf16_rn(Bv.w) };
        u16x4 pd = { bf16_rn(A.x - Bv.x), bf16_rn(A.y - Bv.y),
                     bf16_rn(A.z - Bv.z), bf16_rn(A.w - Bv.w) };
        *(u16x4*)(xlb + i) = pa;
        *(u16x4*)(xrb + i) = pb;
        *(u16x4*)(xdb + i) = pd;
    } else {
        const int gid = (bid - 2048) * 256 + threadIdx.x;   // 0 .. 262143
        const int m = gid >> 16;
        const int idx = gid & 65535;
        const int k = idx >> 8, n = idx & 255;
        const float* W = (m == 0) ? Wq : (m == 1) ? Wk : (m == 2) ? Wv : Wp;
        unsigned short* Wt = (m == 0) ? Wqt : (m == 1) ? Wkt : (m == 2) ? Wvt : Wpt;
        Wt[n * 256 + k] = bf16_rn(W[(size_t)k * 256 + n]);
    }
}

// ---------------------------------------------------------------------------
// 2) QKV projection GEMM: [8192,256] x [256,256] + bias, 3 outputs (z-dim)
//    dbuf staging, 1 barrier per K-step
// ---------------------------------------------------------------------------
__launch_bounds__(256)
__global__ void qkv_gemm(const unsigned short* __restrict__ xlb,
                         const unsigned short* __restrict__ xrb,
                         const unsigned short* __restrict__ xdb,
                         const unsigned short* __restrict__ Wqt,
                         const unsigned short* __restrict__ Wkt,
                         const unsigned short* __restrict__ Wvt,
                         const float* __restrict__ bq, const float* __restrict__ bk,
                         const float* __restrict__ bv,
                         unsigned short* __restrict__ Qg, unsigned short* __restrict__ Kg,
                         unsigned short* __restrict__ Vtg) {
    const int z = blockIdx.z;
    const unsigned short* A  = (z == 0) ? xlb : (z == 1) ? xrb : xdb;
    const unsigned short* Wt = (z == 0) ? Wqt : (z == 1) ? Wkt : Wvt;
    const float* bias        = (z == 0) ? bq  : (z == 1) ? bk  : bv;

    __shared__ unsigned short At[2][128][40];
    __shared__ unsigned short Bt[2][64][40];

    const int tid = threadIdx.x;
    const int lane = tid & 63, wv = tid >> 6;
    const int a = lane & 15, g = lane >> 4;
    const int wr = wv >> 1, wc = wv & 1;
    const int r0 = blockIdx.x * 128;
    const int c0 = blockIdx.y * 64;

    const f32x4 fz = {0.f, 0.f, 0.f, 0.f};
    f32x4 acc[4][2];
#pragma unroll
    for (int f = 0; f < 4; ++f)
#pragma unroll
        for (int t = 0; t < 2; ++t) acc[f][t] = fz;

    const int arow = tid >> 1, aoff = (tid & 1) * 16;
    const int brow = tid >> 2, boff = (tid & 3) * 8;
    const unsigned short* asrc = A + (size_t)(r0 + arow) * 256 + aoff;
    const unsigned short* bsrc = Wt + (size_t)(c0 + brow) * 256 + boff;

#define QKV_STAGE(KS, BUF)                                                      \
    {                                                                           \
        *(short8*)&At[BUF][arow][aoff]     = *(const short8*)(asrc + (KS) * 32); \
        *(short8*)&At[BUF][arow][aoff + 8] = *(const short8*)(asrc + (KS) * 32 + 8); \
        *(short8*)&Bt[BUF][brow][boff]     = *(const short8*)(bsrc + (KS) * 32); \
    }

    QKV_STAGE(0, 0)
    __syncthreads();

#pragma unroll
    for (int ks = 0; ks < 8; ++ks) {
        const int b = ks & 1;
        if (ks < 7) QKV_STAGE(ks + 1, b ^ 1)
        short8 af[4], bfr[2];
#pragma unroll
        for (int f = 0; f < 4; ++f) af[f] = *(const short8*)&At[b][wr * 64 + f * 16 + a][g * 8];
#pragma unroll
        for (int t = 0; t < 2; ++t) bfr[t] = *(const short8*)&Bt[b][wc * 32 + t * 16 + a][g * 8];
#pragma unroll
        for (int f = 0; f < 4; ++f)
#pragma unroll
            for (int t = 0; t < 2; ++t) acc[f][t] = mfma16(af[f], bfr[t], acc[f][t]);
        __syncthreads();
    }
#undef QKV_STAGE

    const float scq = 0.17677669529663687f * 1.4426950408889634f;
#pragma unroll
    for (int t = 0; t < 2; ++t) {
        const int C = c0 + wc * 32 + t * 16 + a;
        const float bb = bias[C];
        const int h = C >> 5, d = C & 31;
#pragma unroll
        for (int f = 0; f < 4; ++f) {
            const int Rb = r0 + wr * 64 + f * 16 + g * 4;
            const int b_ = Rb >> 11, n = Rb & 2047;
            const int bhh = b_ * 8 + h;
            float v[4];
#pragma unroll
            for (int r = 0; r < 4; ++r) {
                v[r] = acc[f][t][r] + bb;
                if (z == 0) v[r] *= scq;
            }
            if (z < 2) {
                unsigned short* dst = ((z == 0) ? Qg : Kg) + (size_t)(bhh * 2048 + n) * 32 + d;
#pragma unroll
                for (int r = 0; r < 4; ++r) dst[(size_t)r * 32] = bf16_rn(v[r]);
            } else {
                u16x4 pk = { bf16_rn(v[0]), bf16_rn(v[1]), bf16_rn(v[2]), bf16_rn(v[3]) };
                *(u16x4*)(Vtg + (size_t)(bhh * 32 + d) * 2048 + n) = pk;
            }
        }
    }
}

// ---------------------------------------------------------------------------
// 3) pass 1: flash attention (exp2 domain, no shift) -> out_l + Vs = V/l
//    8 waves: qi (q-subtile), z (k-half). 64-k phases, 4 LDS tile buffers.
// ---------------------------------------------------------------------------
#define P1_TILE(SB)                                                             \
    {                                                                           \
        const short8 ck0 = *(const short8*)((SB) + ro);                         \
        const short8 ck1 = *(const short8*)((SB) + 512 + ro);                   \
        const short8 cv0 = *(const short8*)((SB) + 1024 + ro);                  \
        const short8 cv1 = *(const short8*)((SB) + 1536 + ro);                  \
        f32x16 s = {};                                                          \
        s = mfma32(ck0, qf0, s);                                                \
        s = mfma32(ck1, qf1, s);                                                \
        float p[16];                                                            \
        _Pragma("unroll") for (int j = 0; j < 16; ++j) p[j] = fexp2(s[j]);      \
        l_run += (((p[0] + p[1]) + (p[2] + p[3])) + ((p[4] + p[5]) + (p[6] + p[7]))) \
               + (((p[8] + p[9]) + (p[10] + p[11])) + ((p[12] + p[13]) + (p[14] + p[15]))); \
        unsigned int w[8];                                                      \
        _Pragma("unroll") for (int mm = 0; mm < 8; ++mm)                        \
            asm("v_cvt_pk_bf16_f32 %0, %1, %2"                                  \
                : "=v"(w[mm]) : "v"(p[2 * mm]), "v"(p[2 * mm + 1]));            \
        acc = mfma32(cv0, pfrag(w[0], w[1], w[2], w[3]), acc);                  \
        acc = mfma32(cv1, pfrag(w[4], w[5], w[6], w[7]), acc);                  \
    }

__launch_bounds__(512, 4)
__global__ void attn_pass1(const unsigned short* __restrict__ Qg,
                           const unsigned short* __restrict__ Kg,
                           const unsigned short* __restrict__ Vtg,
                           unsigned short* __restrict__ AOl,
                           unsigned short* __restrict__ Vsg) {
    __shared__ unsigned short ST[2][2][2][2][2][64][8];  // [z][pbuf][sub][kv][c][slot][e] 32KB
    __shared__ float accS[4][16][64];                    // 16KB
    __shared__ float lsumS[4][64];                       // 1KB

    const int f = blockIdx.x;
    const int bh = 4 * (f & 7) + (f >> 7);
    const int qblk = (f >> 3) & 15;
    const int tid = threadIdx.x;
    const int wv = tid >> 6;
    const int qi = wv & 3, z = wv >> 2;
    const int lane = tid & 63, l31 = lane & 31, hi = lane >> 5;
    const int q0 = qblk * 128 + qi * 32;

    const unsigned short* Qb = Qg + (size_t)bh * 2048 * 32;
    const unsigned short* Kb = Kg + (size_t)bh * 2048 * 32;
    const unsigned short* Vb = Vtg + (size_t)bh * 32 * 2048;

    const short8 qf0 = *(const short8*)(Qb + (size_t)(q0 + l31) * 32 + hi * 8);
    const short8 qf1 = *(const short8*)(Qb + (size_t)(q0 + l31) * 32 + 16 + hi * 8);

    // staging geometry: qi<2 -> K rows, qi>=2 -> V rows (16 rows per wave)
    const int kv = qi >> 1;
    const int srow = (qi & 1) * 16 + (lane >> 2);
    const int m = lane & 3;
    unsigned short* wp00 = &ST[z][0][0][kv][m >> 1][srow + 32 * (m & 1)][0];
    unsigned short* wp01 = &ST[z][0][1][kv][m >> 1][srow + 32 * (m & 1)][0];
    unsigned short* wp10 = &ST[z][1][0][kv][m >> 1][srow + 32 * (m & 1)][0];
    unsigned short* wp11 = &ST[z][1][1][kv][m >> 1][srow + 32 * (m & 1)][0];
    const size_t gstep = kv ? 32 : 1024;               // per-tile element step
    const unsigned short* sgb = kv
        ? Vb + (size_t)srow * 2048 + m * 8
        : Kb + (size_t)srow * 32 + m * 8;
    const int zt = z * 32;

    const unsigned short* rb00 = &ST[z][0][0][0][0][0][0];
    const unsigned short* rb01 = &ST[z][0][1][0][0][0][0];
    const unsigned short* rb10 = &ST[z][1][0][0][0][0][0];
    const unsigned short* rb11 = &ST[z][1][1][0][0][0][0];
    const int ro = (l31 + 32 * hi) * 8;

    f32x16 acc = {};
    float l_run = 0.f;

    // prologue: tiles 0,1 -> pbuf0; tiles 2,3 -> regs
    short8 rr0 = *(const short8*)(sgb + (size_t)(zt + 0) * gstep);
    short8 rr1 = *(const short8*)(sgb + (size_t)(zt + 1) * gstep);
    *(short8*)wp00 = rr0;
    *(short8*)wp01 = rr1;
    rr0 = *(const short8*)(sgb + (size_t)(zt + 2) * gstep);
    rr1 = *(const short8*)(sgb + (size_t)(zt + 3) * gstep);
    __syncthreads();

#pragma unroll
    for (int ph = 0; ph < 16; ++ph) {
        const int pb = ph & 1;
        unsigned short* wA = pb ? wp00 : wp10;
        unsigned short* wB = pb ? wp01 : wp11;
        const unsigned short* rA = pb ? rb10 : rb00;
        const unsigned short* rB = pb ? rb11 : rb01;
        if (ph < 15) { *(short8*)wA = rr0; *(short8*)wB = rr1; }
        if (ph < 14) {
            rr0 = *(const short8*)(sgb + (size_t)(zt + 2 * ph + 4) * gstep);
            rr1 = *(const short8*)(sgb + (size_t)(zt + 2 * ph + 5) * gstep);
        }
        P1_TILE(rA)
        P1_TILE(rB)
        __syncthreads();
    }

    float lsum = l_run + __shfl_xor(l_run, 32);

    if (z == 1) {
#pragma unroll
        for (int j = 0; j < 16; ++j) accS[qi][j][lane] = acc[j];
        lsumS[qi][lane] = lsum;
    }
    __syncthreads();
    if (z == 0) {
        lsum += lsumS[qi][lane];
        const float rl = 1.0f / lsum;
#pragma unroll
        for (int j = 0; j < 16; ++j) acc[j] += accS[qi][j][lane];

        const int b_ = bh >> 3, h = bh & 7;
        const int q = q0 + l31;
        unsigned short* dst = AOl + (size_t)(b_ * 2048 + q) * 256 + h * 32;
#pragma unroll
        for (int g2 = 0; g2 < 4; ++g2) {
            u16x4 pk = { bf16_rn(acc[4 * g2 + 0] * rl), bf16_rn(acc[4 * g2 + 1] * rl),
                         bf16_rn(acc[4 * g2 + 2] * rl), bf16_rn(acc[4 * g2 + 3] * rl) };
            *(u16x4*)(dst + 8 * g2 + 4 * hi) = pk;
        }
        if (hi == 0) lsumS[qi][l31] = rl;   // rl for column q0+l31
    }
    __syncthreads();
    if (z == 1) {
        // scale V columns [q0, q0+32) by rl: lane (l31,hi) -> d=l31, 16 cols
        const int cb = hi * 16;
        float il[16];
#pragma unroll
        for (int e = 0; e < 16; e += 4) {
            const float4 v4 = *(const float4*)&lsumS[qi][cb + e];
            il[e] = v4.x; il[e + 1] = v4.y; il[e + 2] = v4.z; il[e + 3] = v4.w;
        }
        const unsigned short* vsrc = Vb + (size_t)l31 * 2048 + q0 + cb;
        unsigned short* vdst = Vsg + (size_t)bh * 32 * 2048 + (size_t)l31 * 2048 + q0 + cb;
#pragma unroll
        for (int c4 = 0; c4 < 4; ++c4) {
            const u16x4 vv = *(const u16x4*)(vsrc + c4 * 4);
            u16x4 o = { bf16_rn(b2f(vv.x) * il[c4 * 4 + 0]),
                        bf16_rn(b2f(vv.y) * il[c4 * 4 + 1]),
                        bf16_rn(b2f(vv.z) * il[c4 * 4 + 2]),
                        bf16_rn(b2f(vv.w) * il[c4 * 4 + 3]) };
            *(u16x4*)(vdst + c4 * 4) = o;
        }
    }
}

// ---------------------------------------------------------------------------
// 4) pass 2: out_r = exp2(S)^T @ Vs  (Vs pre-normalized). Same structure.
// ---------------------------------------------------------------------------
#define P2_TILE(SB)                                                             \
    {                                                                           \
        const short8 cq0 = *(const short8*)((SB) + ro);                         \
        const short8 cq1 = *(const short8*)((SB) + 512 + ro);                   \
        const short8 cv0 = *(const short8*)((SB) + 1024 + ro);                  \
        const short8 cv1 = *(const short8*)((SB) + 1536 + ro);                  \
        f32x16 s = {};                                                          \
        s = mfma32(cq0, kf0, s);                                                \
        s = mfma32(cq1, kf1, s);                                                \
        float p[16];                                                            \
        _Pragma("unroll") for (int j = 0; j < 16; ++j) p[j] = fexp2(s[j]);      \
        unsigned int w[8];                                                      \
        _Pragma("unroll") for (int mm = 0; mm < 8; ++mm)                        \
            asm("v_cvt_pk_bf16_f32 %0, %1, %2"                                  \
                : "=v"(w[mm]) : "v"(p[2 * mm]), "v"(p[2 * mm + 1]));            \
        acc = mfma32(pfrag(w[0], w[1], w[2], w[3]), cv0, acc);                  \
        acc = mfma32(pfrag(w[4], w[5], w[6], w[7]), cv1, acc);                  \
    }

__launch_bounds__(512, 4)
__global__ void attn_pass2(const unsigned short* __restrict__ Qg,
                           const unsigned short* __restrict__ Kg,
                           const unsigned short* __restrict__ Vsg,
                           unsigned short* __restrict__ AOr) {
    __shared__ unsigned short ST[2][2][2][2][2][64][8];
    __shared__ float accS[4][16][64];

    const int f = blockIdx.x;
    const int bh = 4 * (f & 7) + (f >> 7);
    const int kblk = (f >> 3) & 15;
    const int tid = threadIdx.x;
    const int wv = tid >> 6;
    const int ki = wv & 3, z = wv >> 2;
    const int lane = tid & 63, l31 = lane & 31, hi = lane >> 5;
    const int k0 = kblk * 128 + ki * 32;

    const unsigned short* Qb = Qg + (size_t)bh * 2048 * 32;
    const unsigned short* Kb = Kg + (size_t)bh * 2048 * 32;
    const unsigned short* Vb = Vsg + (size_t)bh * 32 * 2048;

    const short8 kf0 = *(const short8*)(Kb + (size_t)(k0 + l31) * 32 + hi * 8);
    const short8 kf1 = *(const short8*)(Kb + (size_t)(k0 + l31) * 32 + 16 + hi * 8);

    const int kv = ki >> 1;
    const int srow = (ki & 1) * 16 + (lane >> 2);
    const int m = lane & 3;
    unsigned short* wp00 = &ST[z][0][0][kv][m >> 1][srow + 32 * (m & 1)][0];
    unsigned short* wp01 = &ST[z][0][1][kv][m >> 1][srow + 32 * (m & 1)][0];
    unsigned short* wp10 = &ST[z][1][0][kv][m >> 1][srow + 32 * (m & 1)][0];
    unsigned short* wp11 = &ST[z][1][1][kv][m >> 1][srow + 32 * (m & 1)][0];
    const size_t gstep = kv ? 32 : 1024;
    const unsigned short* sgb = kv
        ? Vb + (size_t)srow * 2048 + m * 8
        : Qb + (size_t)srow * 32 + m * 8;
    const int zt = z * 32;

    const unsigned short* rb00 = &ST[z][0][0][0][0][0][0];
    const unsigned short* rb01 = &ST[z][0][1][0][0][0][0];
    const unsigned short* rb10 = &ST[z][1][0][0][0][0][0];
    const unsigned short* rb11 = &ST[z][1][1][0][0][0][0];
    const int ro = (l31 + 32 * hi) * 8;

    f32x16 acc = {};

    short8 rr0 = *(const short8*)(sgb + (size_t)(zt + 0) * gstep);
    short8 rr1 = *(const short8*)(sgb + (size_t)(zt + 1) * gstep);
    *(short8*)wp00 = rr0;
    *(short8*)wp01 = rr1;
    rr0 = *(const short8*)(sgb + (size_t)(zt + 2) * gstep);
    rr1 = *(const short8*)(sgb + (size_t)(zt + 3) * gstep);
    __syncthreads();

#pragma unroll
    for (int ph = 0; ph < 16; ++ph) {
        const int pb = ph & 1;
        unsigned short* wA = pb ? wp00 : wp10;
        unsigned short* wB = pb ? wp01 : wp11;
        const unsigned short* rA = pb ? rb10 : rb00;
        const unsigned short* rB = pb ? rb11 : rb01;
        if (ph < 15) { *(short8*)wA = rr0; *(short8*)wB = rr1; }
        if (ph < 14) {
            rr0 = *(const short8*)(sgb + (size_t)(zt + 2 * ph + 4) * gstep);
            rr1 = *(const short8*)(sgb + (size_t)(zt + 2 * ph + 5) * gstep);
        }
        P2_TILE(rA)
        P2_TILE(rB)
        __syncthreads();
    }

    if (z == 1) {
#pragma unroll
        for (int j = 0; j < 16; ++j) accS[ki][j][lane] = acc[j];
    }
    __syncthreads();
    if (z == 0) {
#pragma unroll
        for (int j = 0; j < 16; ++j) acc[j] += accS[ki][j][lane];

        const int b_ = bh >> 3, h = bh & 7;
#pragma unroll
        for (int j = 0; j < 16; ++j) {
            const int krow = k0 + (j & 3) + 8 * (j >> 2) + 4 * hi;
            AOr[(size_t)(b_ * 2048 + krow) * 256 + h * 32 + l31] = bf16_rn(acc[j]);
        }
    }
}

// ---------------------------------------------------------------------------
// 5) output projection + LayerNorm + residual, L/R fused (blockIdx.y)
//    Bt double-buffered: 1 barrier per K-step
// ---------------------------------------------------------------------------
__launch_bounds__(256)
__global__ void proj_ln(const unsigned short* __restrict__ AOl,
                        const unsigned short* __restrict__ AOr,
                        const unsigned short* __restrict__ Wpt,
                        const float* __restrict__ bp,
                        const float* __restrict__ ln_g, const float* __restrict__ ln_b,
                        const float* __restrict__ rn_g, const float* __restrict__ rn_b,
                        const float* __restrict__ xl, const float* __restrict__ xr,
                        float* __restrict__ out) {
    __shared__ unsigned short At[64][264];
    __shared__ unsigned short Bt[2][256][40];

    const int sel = blockIdx.y;
    const unsigned short* AO = sel ? AOr : AOl;
    const float* gamma = sel ? rn_g : ln_g;
    const float* beta  = sel ? rn_b : ln_b;
    const float* xres  = sel ? xr : xl;
    float* o = out + (size_t)sel * 8192 * 256;

    const int tid = threadIdx.x;
    const int lane = tid & 63, wv = tid >> 6;
    const int a = lane & 15, g = lane >> 4;
    const int r0 = blockIdx.x * 64;

    {
        const int row = tid >> 2, seg = (tid & 3) * 64;
        const unsigned short* src = AO + (size_t)(r0 + row) * 256 + seg;
#pragma unroll
        for (int i = 0; i < 8; ++i)
            *(short8*)&At[row][seg + i * 8] = *(const short8*)(src + i * 8);
    }
    const unsigned short* wsrc = Wpt + (size_t)tid * 256;
    {
#pragma unroll
        for (int i = 0; i < 4; ++i)
            *(short8*)&Bt[0][tid][i * 8] = *(const short8*)(wsrc + i * 8);
    }

    const f32x4 fz = {0.f, 0.f, 0.f, 0.f};
    f32x4 acc[16];
#pragma unroll
    for (int cf = 0; cf < 16; ++cf) acc[cf] = fz;

    __syncthreads();

#pragma unroll
    for (int ks = 0; ks < 8; ++ks) {
        const int b = ks & 1;
        if (ks < 7) {
#pragma unroll
            for (int i = 0; i < 4; ++i)
                *(short8*)&Bt[b ^ 1][tid][i * 8] =
                    *(const short8*)(wsrc + (ks + 1) * 32 + i * 8);
        }
        const short8 af = *(const short8*)&At[wv * 16 + a][ks * 32 + g * 8];
#pragma unroll
        for (int cf = 0; cf < 16; ++cf) {
            const short8 bfr = *(const short8*)&Bt[b][cf * 16 + a][g * 8];
            acc[cf] = mfma16(af, bfr, acc[cf]);
        }
        __syncthreads();
    }

    float bb[16], gg[16], be[16];
#pragma unroll
    for (int cf = 0; cf < 16; ++cf) {
        const int c = cf * 16 + a;
        bb[cf] = bp[c]; gg[cf] = gamma[c]; be[cf] = beta[c];
    }
#pragma unroll
    for (int r = 0; r < 4; ++r) {
        float y[16];
        float s1 = 0.f, s2 = 0.f;
#pragma unroll
        for (int cf = 0; cf < 16; ++cf) {
            y[cf] = acc[cf][r] + bb[cf];
            s1 += y[cf];
            s2 += y[cf] * y[cf];
        }
#pragma unroll
        for (int mask = 1; mask <= 8; mask <<= 1) {
            s1 += __shfl_xor(s1, mask);
            s2 += __shfl_xor(s2, mask);
        }
        const float mu = s1 * (1.0f / 256.0f);
        const float var = s2 * (1.0f / 256.0f) - mu * mu;
        const float rstd = rsqrtf(var + 1e-5f);
        const int R = r0 + wv * 16 + g * 4 + r;
#pragma unroll
        for (int cf = 0; cf < 16; ++cf) {
            const int c = cf * 16 + a;
            o[(size_t)R * 256 + c] =
                (y[cf] - mu) * rstd * gg[cf] + be[cf] + xres[(size_t)R * 256 + c];
        }
    }
}

// ---------------------------------------------------------------------------
extern "C" void kernel_launch(void* const* d_in, const int* in_sizes, int n_in,
                              void* d_out, int out_size, void* d_ws, size_t ws_size,
                              hipStream_t stream) {
    const float* x_l  = (const float*)d_in[0];
    const float* x_r  = (const float*)d_in[1];
    const float* Wq   = (const float*)d_in[2];
    const float* bq   = (const float*)d_in[3];
    const float* Wk   = (const float*)d_in[4];
    const float* bk   = (const float*)d_in[5];
    const float* Wv   = (const float*)d_in[6];
    const float* bv   = (const float*)d_in[7];
    const float* Wp   = (const float*)d_in[8];
    const float* bp   = (const float*)d_in[9];
    const float* ln_g = (const float*)d_in[10];
    const float* ln_b = (const float*)d_in[11];
    const float* rn_g = (const float*)d_in[12];
    const float* rn_b = (const float*)d_in[13];

    const size_t SZ_TOK = (size_t)8192 * 256;

    unsigned short* xl_bf = (unsigned short*)d_ws;
    unsigned short* xr_bf = xl_bf + SZ_TOK;
    unsigned short* xd_bf = xr_bf + SZ_TOK;
    unsigned short* Qg    = xd_bf + SZ_TOK;
    unsigned short* Kg    = Qg + SZ_TOK;
    unsigned short* Vtg   = Kg + SZ_TOK;
    unsigned short* Wqt   = Vtg + SZ_TOK;
    unsigned short* Wkt   = Wqt + 65536;
    unsigned short* Wvt   = Wkt + 65536;
    unsigned short* Wpt   = Wvt + 65536;
    unsigned short* AOl   = xl_bf;   // qkv_gemm (last reader of xl) precedes pass1
    unsigned short* AOr   = xr_bf;
    unsigned short* Vs    = xd_bf;   // xd dead after qkv_gemm
    float* out = (float*)d_out;

    prep_all<<<3072, 256, 0, stream>>>(x_l, x_r, Wq, Wk, Wv, Wp,
                                       xl_bf, xr_bf, xd_bf, Wqt, Wkt, Wvt, Wpt);
    qkv_gemm<<<dim3(64, 4, 3), 256, 0, stream>>>(xl_bf, xr_bf, xd_bf,
                                                 Wqt, Wkt, Wvt, bq, bk, bv, Qg, Kg, Vtg);
    attn_pass1<<<512, 512, 0, stream>>>(Qg, Kg, Vtg, AOl, Vs);
    attn_pass2<<<512, 512, 0, stream>>>(Qg, Kg, Vs, AOr);
    proj_ln<<<dim3(128, 2), 256, 0, stream>>>(AOl, AOr, Wpt, bp,
                                              ln_g, ln_b, rn_g, rn_b, x_l, x_r, out);
}